// Round 5
// baseline (515.552 us; speedup 1.0000x reference)
//
#include <hip/hip_runtime.h>
#include <math.h>

#define NN 50000
#define NE 800000
#define NBLK 49   // ceil(NN/1024)

// ---------------- degree / CSR build ----------------

__global__ __launch_bounds__(256) void k_deg(const int* __restrict__ dst, int* __restrict__ deg) {
  int e = blockIdx.x * 256 + threadIdx.x;
  if (e < NE) atomicAdd(&deg[dst[e]], 1);
}

__global__ __launch_bounds__(1024) void k_scan1(const int* __restrict__ deg, int* __restrict__ excl,
                                                int* __restrict__ blksum) {
  __shared__ int sm[1024];
  int t = threadIdx.x;
  int i = blockIdx.x * 1024 + t;
  int v = (i < NN) ? deg[i] : 0;
  sm[t] = v;
  __syncthreads();
  for (int off = 1; off < 1024; off <<= 1) {
    int x = (t >= off) ? sm[t - off] : 0;
    __syncthreads();
    sm[t] += x;
    __syncthreads();
  }
  if (i < NN) excl[i] = sm[t] - v;
  if (t == 1023) blksum[blockIdx.x] = sm[t];
}

__global__ void k_scan2(const int* __restrict__ blksum, int* __restrict__ blkoff,
                        int* __restrict__ rowstart) {
  int t = threadIdx.x;  // 64 threads, one wave
  int orig = (t < NBLK) ? blksum[t] : 0;
  int v = orig;
  #pragma unroll
  for (int off = 1; off < 64; off <<= 1) {
    int u = __shfl_up(v, off);
    if (t >= off) v += u;
  }
  if (t < NBLK) blkoff[t] = v - orig;
  if (t == NBLK - 1) rowstart[NN] = v;  // == NE
}

// also computes dis[]
__global__ __launch_bounds__(256) void k_scan3(int* __restrict__ excl, const int* __restrict__ blkoff,
                                               const int* __restrict__ deg, float* __restrict__ dis) {
  int i = blockIdx.x * 256 + threadIdx.x;
  if (i < NN) {
    excl[i] += blkoff[i >> 10];
    dis[i] = rsqrtf((float)deg[i] + 1.0f);
  }
}

__global__ __launch_bounds__(256) void k_fill(const int* __restrict__ src, const int* __restrict__ dst,
                                              const int* __restrict__ rowstart, int* __restrict__ cursor,
                                              int* __restrict__ csr_src) {
  int e = blockIdx.x * 256 + threadIdx.x;
  if (e < NE) {
    int d = dst[e];
    int p = atomicAdd(&cursor[d], 1);
    csr_src[rowstart[d] + p] = src[e];
  }
}

// ---------------- SGEMM: H = X @ W, epilogue scales row by dis[row] ----------------
// NC==128: writes slice-major Hs[slice][node][16], fp32 (slice = col>>4).
// NC==32 : writes row-major fp32 [node][32].

template <int NC>
__global__ __launch_bounds__(256) void k_gemm(const float* __restrict__ X, const float* __restrict__ W,
                                              const float* __restrict__ dis, float* __restrict__ Hout, int M) {
  constexpr int TN = NC / 16;
  __shared__ float As[8][128];
  __shared__ float Bs[8][NC];
  const int tid = threadIdx.x;
  const int rg = tid >> 4;   // 0..15
  const int cg = tid & 15;   // 0..15
  const int row0 = blockIdx.x * 128;

  float acc[8][TN];
  #pragma unroll
  for (int i = 0; i < 8; i++)
    #pragma unroll
    for (int j = 0; j < TN; j++) acc[i][j] = 0.f;

  const int lr = tid >> 1;         // 0..127 row in tile
  const int lk = (tid & 1) * 4;    // 0 or 4

  for (int kt = 0; kt < 128; kt += 8) {
    float4 av = make_float4(0.f, 0.f, 0.f, 0.f);
    int gr = row0 + lr;
    if (gr < M) av = *(const float4*)(X + (size_t)gr * 128 + kt + lk);
    As[lk + 0][lr] = av.x; As[lk + 1][lr] = av.y; As[lk + 2][lr] = av.z; As[lk + 3][lr] = av.w;
    if constexpr (NC == 128) {
      int k = tid >> 5, c = (tid & 31) * 4;
      *(float4*)&Bs[k][c] = *(const float4*)(W + (size_t)(k + kt) * 128 + c);
    } else {  // NC == 32
      int k = tid >> 5, c = tid & 31;
      Bs[k][c] = W[(size_t)(k + kt) * NC + c];
    }
    __syncthreads();
    #pragma unroll
    for (int kk = 0; kk < 8; kk++) {
      float a[8];
      *(float4*)&a[0] = *(const float4*)&As[kk][rg * 8];
      *(float4*)&a[4] = *(const float4*)&As[kk][rg * 8 + 4];
      float b[TN];
      if constexpr (TN == 8) {
        *(float4*)&b[0] = *(const float4*)&Bs[kk][cg * 8];
        *(float4*)&b[4] = *(const float4*)&Bs[kk][cg * 8 + 4];
      } else {
        b[0] = Bs[kk][cg * 2]; b[1] = Bs[kk][cg * 2 + 1];
      }
      #pragma unroll
      for (int i = 0; i < 8; i++)
        #pragma unroll
        for (int j = 0; j < TN; j++) acc[i][j] += a[i] * b[j];
    }
    __syncthreads();
  }

  #pragma unroll
  for (int i = 0; i < 8; i++) {
    int gr = row0 + rg * 8 + i;
    if (gr < M) {
      float d = dis[gr];
      if constexpr (TN == 8) {
        // columns cg*8 .. cg*8+7 -> slice = cg>>1, within-slice col = (cg&1)*8
        size_t sbase = (size_t)(cg >> 1) * ((size_t)NN * 16) + (size_t)gr * 16 + (cg & 1) * 8;
        *(float4*)(Hout + sbase)     = make_float4(acc[i][0] * d, acc[i][1] * d, acc[i][2] * d, acc[i][3] * d);
        *(float4*)(Hout + sbase + 4) = make_float4(acc[i][4] * d, acc[i][5] * d, acc[i][6] * d, acc[i][7] * d);
      } else {
        *(float2*)(Hout + (size_t)gr * NC + cg * 2) = make_float2(acc[i][0] * d, acc[i][1] * d);
      }
    }
  }
}

// ---------------- aggregation, layer 0/1: XCD-sliced, shuffle-free ----------------
// slice = blockIdx & 7 (round-robin -> XCD); slice-major Hs: 3.2 MB resident/XCD.
// Wave = 8 nodes x 8 feature-lanes; each lane walks its node's CSR row serially
// (unrolled x2 for MLP), owns its float2 accumulator, writes directly. No
// cross-lane ops at all. Hs pre-scaled by dis[src]:
//   out = (sum Hs[src] + Hs[w]) * dis[w] + bias.

__global__ __launch_bounds__(256) void k_agg128(const float* __restrict__ Hs,
                                                const float* __restrict__ dis,
                                                const int* __restrict__ rowstart,
                                                const int* __restrict__ csr_src,
                                                const float* __restrict__ bias,
                                                float* __restrict__ out) {
  int slice = blockIdx.x & 7;
  int lane = threadIdx.x & 63;
  int node_sub = lane >> 3;      // 0..7: which node within the wave
  int fl = lane & 7;             // 0..7: feature pair within the slice
  int w = (blockIdx.x >> 3) * 32 + (threadIdx.x >> 6) * 8 + node_sub;
  if (w >= NN) return;           // per-lane guard; no cross-lane ops below
  const float* __restrict__ S = Hs + (size_t)slice * ((size_t)NN * 16) + fl * 2;
  float di = dis[w];
  int e0 = rowstart[w], e1 = rowstart[w + 1];
  float ax = 0.f, ay = 0.f;
  int e = e0;
  for (; e + 2 <= e1; e += 2) {
    int s0 = csr_src[e];
    int s1 = csr_src[e + 1];
    float2 g0 = *(const float2*)(S + (size_t)s0 * 16);
    float2 g1 = *(const float2*)(S + (size_t)s1 * 16);
    ax += g0.x + g1.x;
    ay += g0.y + g1.y;
  }
  if (e < e1) {
    int s = csr_src[e];
    float2 g = *(const float2*)(S + (size_t)s * 16);
    ax += g.x;
    ay += g.y;
  }
  float2 selfv = *(const float2*)(S + (size_t)w * 16);
  int colOff = slice * 16 + fl * 2;
  float ox = (ax + selfv.x) * di + bias[colOff];
  float oy = (ay + selfv.y) * di + bias[colOff + 1];
  *(float2*)(out + (size_t)w * 128 + colOff) = make_float2(ox, oy);
}

// final layer: 2 nodes per wave, fp32 H2 pre-scaled by dis[src] (R2-proven structure)
__global__ __launch_bounds__(256) void k_agg32(const float* __restrict__ H2,
                                               const float* __restrict__ dis,
                                               const int* __restrict__ rowstart,
                                               const int* __restrict__ csr_src,
                                               const float* __restrict__ bias,
                                               float* __restrict__ out) {
  int pairWave = (blockIdx.x * 256 + threadIdx.x) >> 6;
  int lane = threadIdx.x & 63;
  int half = lane >> 5;
  int l = lane & 31;
  int w = pairWave * 2 + half;
  if (w >= NN) return;
  float di = dis[w];
  int e0 = rowstart[w], e1 = rowstart[w + 1];
  float acc = 0.f;

  for (int base = e0; base < e1; base += 32) {
    int cnt = e1 - base; if (cnt > 32) cnt = 32;
    int myS = (base + l < e1) ? csr_src[base + l] : 0;
    int j = 0;
    for (; j + 4 <= cnt; j += 4) {
      int s0 = __shfl(myS, j, 32),     s1 = __shfl(myS, j + 1, 32);
      int s2 = __shfl(myS, j + 2, 32), s3 = __shfl(myS, j + 3, 32);
      float h0 = H2[(size_t)s0 * 32 + l];
      float h1 = H2[(size_t)s1 * 32 + l];
      float h2 = H2[(size_t)s2 * 32 + l];
      float h3 = H2[(size_t)s3 * 32 + l];
      acc += h0 + h1 + h2 + h3;
    }
    for (; j < cnt; j++) {
      int s = __shfl(myS, j, 32);
      acc += H2[(size_t)s * 32 + l];
    }
  }
  acc = (acc + H2[(size_t)w * 32 + l]) * di + bias[l];
  out[(size_t)w * 32 + l] = acc;
}

// ---------------- BatchNorm stats + fused BN/ReLU/residual ----------------

__global__ __launch_bounds__(256) void k_bnstats(const float* __restrict__ O, float* __restrict__ gsum,
                                                 float* __restrict__ gsumsq) {
  int tid = threadIdx.x;
  int f = tid & 127;
  int half = tid >> 7;
  float s = 0.f, sq = 0.f;
  for (int r = blockIdx.x * 2 + half; r < NN; r += gridDim.x * 2) {
    float v = O[(size_t)r * 128 + f];
    s += v; sq += v * v;
  }
  __shared__ float sm[256], sm2[256];
  sm[tid] = s; sm2[tid] = sq;
  __syncthreads();
  if (tid < 128) {
    atomicAdd(&gsum[f], sm[tid] + sm[tid + 128]);
    atomicAdd(&gsumsq[f], sm2[tid] + sm2[tid + 128]);
  }
}

__global__ void k_bnfinal(const float* __restrict__ gsum, const float* __restrict__ gsumsq,
                          float* __restrict__ mu, float* __restrict__ istd) {
  int f = threadIdx.x;  // 128
  float m = gsum[f] / (float)NN;
  float v = gsumsq[f] / (float)NN - m * m;
  mu[f] = m;
  istd[f] = rsqrtf(v + 1e-5f);
}

__global__ __launch_bounds__(256) void k_fuse(const float* __restrict__ O, const float* Xin, float* Xout,
                                              const float* __restrict__ mu, const float* __restrict__ istd,
                                              const float* __restrict__ g, const float* __restrict__ be) {
  int i = blockIdx.x * 256 + threadIdx.x;
  if (i >= NN * 128 / 4) return;
  int f = (i * 4) & 127;
  float4 ov = ((const float4*)O)[i];
  float4 xv = ((const float4*)Xin)[i];
  float4 r;
  r.x = fmaxf((ov.x - mu[f + 0]) * istd[f + 0] * g[f + 0] + be[f + 0], 0.f) + xv.x;
  r.y = fmaxf((ov.y - mu[f + 1]) * istd[f + 1] * g[f + 1] + be[f + 1], 0.f) + xv.y;
  r.z = fmaxf((ov.z - mu[f + 2]) * istd[f + 2] * g[f + 2] + be[f + 2], 0.f) + xv.z;
  r.w = fmaxf((ov.w - mu[f + 3]) * istd[f + 3] * g[f + 3] + be[f + 3], 0.f) + xv.w;
  ((float4*)Xout)[i] = r;
}

// ---------------- log_softmax over 32 classes, in-place ----------------

__global__ __launch_bounds__(256) void k_lsm(float* __restrict__ out) {
  int w = (blockIdx.x * 256 + threadIdx.x) >> 6;
  int lane = threadIdx.x & 63;
  if (w >= NN) return;
  float v = (lane < 32) ? out[(size_t)w * 32 + lane] : -1e30f;
  float m = v;
  #pragma unroll
  for (int off = 16; off >= 1; off >>= 1) m = fmaxf(m, __shfl_xor(m, off));
  float e = (lane < 32) ? expf(v - m) : 0.f;
  float s = e;
  #pragma unroll
  for (int off = 16; off >= 1; off >>= 1) s += __shfl_xor(s, off);
  if (lane < 32) out[(size_t)w * 32 + lane] = v - m - logf(s);
}

// ---------------- launch ----------------

extern "C" void kernel_launch(void* const* d_in, const int* in_sizes, int n_in,
                              void* d_out, int out_size, void* d_ws, size_t ws_size,
                              hipStream_t stream) {
  const float* x   = (const float*)d_in[0];
  const int*   ei  = (const int*)d_in[1];
  const float* W0  = (const float*)d_in[2];
  const float* b0  = (const float*)d_in[3];
  const float* g0  = (const float*)d_in[4];
  const float* be0 = (const float*)d_in[5];
  const float* W1  = (const float*)d_in[6];
  const float* b1  = (const float*)d_in[7];
  const float* g1  = (const float*)d_in[8];
  const float* be1 = (const float*)d_in[9];
  const float* W2  = (const float*)d_in[10];
  const float* b2  = (const float*)d_in[11];
  float* out = (float*)d_out;
  const int* srcI = ei;
  const int* dstI = ei + NE;

  char* p = (char*)d_ws;
  auto take = [&](size_t bytes) { char* r = p; p += (bytes + 255) & ~(size_t)255; return (void*)r; };
  int*   deg      = (int*)take(NN * 4);
  int*   cursor   = (int*)take(NN * 4);
  int*   rowstart = (int*)take((NN + 1) * 4);
  int*   blksum   = (int*)take(64 * 4);
  int*   blkoff   = (int*)take(64 * 4);
  float* dis      = (float*)take(NN * 4);
  int*   csr      = (int*)take(NE * 4);
  float* gstat    = (float*)take(256 * 4);
  float* mu       = (float*)take(128 * 4);
  float* istd     = (float*)take(128 * 4);
  float* hs       = (float*)take((size_t)NN * 128 * 4);  // fp32, slice-major, pre-scaled
  float* o        = (float*)take((size_t)NN * 128 * 4);
  float* xA       = (float*)take((size_t)NN * 128 * 4);
  float* h2       = (float*)take((size_t)NN * 32 * 4);

  hipMemsetAsync(deg, 0, NN * 4, stream);
  hipMemsetAsync(cursor, 0, NN * 4, stream);

  k_deg<<<(NE + 255) / 256, 256, 0, stream>>>(dstI, deg);
  k_scan1<<<NBLK, 1024, 0, stream>>>(deg, rowstart, blksum);
  k_scan2<<<1, 64, 0, stream>>>(blksum, blkoff, rowstart);
  k_scan3<<<(NN + 255) / 256, 256, 0, stream>>>(rowstart, blkoff, deg, dis);
  k_fill<<<(NE + 255) / 256, 256, 0, stream>>>(srcI, dstI, rowstart, cursor, csr);

  const int aggGrid = ((NN + 31) / 32) * 8;  // 32 nodes/block x 8 slices

  // ---- layer 0 ----
  k_gemm<128><<<(NN + 127) / 128, 256, 0, stream>>>(x, W0, dis, hs, NN);
  k_agg128<<<aggGrid, 256, 0, stream>>>(hs, dis, rowstart, csr, b0, o);
  hipMemsetAsync(gstat, 0, 256 * 4, stream);
  k_bnstats<<<256, 256, 0, stream>>>(o, gstat, gstat + 128);
  k_bnfinal<<<1, 128, 0, stream>>>(gstat, gstat + 128, mu, istd);
  k_fuse<<<(NN * 128 / 4 + 255) / 256, 256, 0, stream>>>(o, x, xA, mu, istd, g0, be0);

  // ---- layer 1 ----
  k_gemm<128><<<(NN + 127) / 128, 256, 0, stream>>>(xA, W1, dis, hs, NN);
  k_agg128<<<aggGrid, 256, 0, stream>>>(hs, dis, rowstart, csr, b1, o);
  hipMemsetAsync(gstat, 0, 256 * 4, stream);
  k_bnstats<<<256, 256, 0, stream>>>(o, gstat, gstat + 128);
  k_bnfinal<<<1, 128, 0, stream>>>(gstat, gstat + 128, mu, istd);
  k_fuse<<<(NN * 128 / 4 + 255) / 256, 256, 0, stream>>>(o, xA, xA, mu, istd, g1, be1);

  // ---- final conv + log_softmax ----
  k_gemm<32><<<(NN + 127) / 128, 256, 0, stream>>>(xA, W2, dis, h2, NN);
  k_agg32<<<(NN + 7) / 8, 256, 0, stream>>>(h2, dis, rowstart, csr, b2, out);
  k_lsm<<<(NN + 3) / 4, 256, 0, stream>>>(out);
}

// Round 6
// 497.156 us; speedup vs baseline: 1.0370x; 1.0370x over previous
//
#include <hip/hip_runtime.h>
#include <math.h>

#define NN 50000
#define NE 800000
#define NBLK 49   // ceil(NN/1024)

// ---------------- degree / CSR build ----------------

__global__ __launch_bounds__(256) void k_deg(const int* __restrict__ dst, int* __restrict__ deg) {
  int e = blockIdx.x * 256 + threadIdx.x;
  if (e < NE) atomicAdd(&deg[dst[e]], 1);
}

__global__ __launch_bounds__(1024) void k_scan1(const int* __restrict__ deg, int* __restrict__ excl,
                                                int* __restrict__ blksum) {
  __shared__ int sm[1024];
  int t = threadIdx.x;
  int i = blockIdx.x * 1024 + t;
  int v = (i < NN) ? deg[i] : 0;
  sm[t] = v;
  __syncthreads();
  for (int off = 1; off < 1024; off <<= 1) {
    int x = (t >= off) ? sm[t - off] : 0;
    __syncthreads();
    sm[t] += x;
    __syncthreads();
  }
  if (i < NN) excl[i] = sm[t] - v;
  if (t == 1023) blksum[blockIdx.x] = sm[t];
}

__global__ void k_scan2(const int* __restrict__ blksum, int* __restrict__ blkoff,
                        int* __restrict__ rowstart) {
  int t = threadIdx.x;  // 64 threads, one wave
  int orig = (t < NBLK) ? blksum[t] : 0;
  int v = orig;
  #pragma unroll
  for (int off = 1; off < 64; off <<= 1) {
    int u = __shfl_up(v, off);
    if (t >= off) v += u;
  }
  if (t < NBLK) blkoff[t] = v - orig;
  if (t == NBLK - 1) rowstart[NN] = v;  // == NE
}

// also computes dis[]
__global__ __launch_bounds__(256) void k_scan3(int* __restrict__ excl, const int* __restrict__ blkoff,
                                               const int* __restrict__ deg, float* __restrict__ dis) {
  int i = blockIdx.x * 256 + threadIdx.x;
  if (i < NN) {
    excl[i] += blkoff[i >> 10];
    dis[i] = rsqrtf((float)deg[i] + 1.0f);
  }
}

__global__ __launch_bounds__(256) void k_fill(const int* __restrict__ src, const int* __restrict__ dst,
                                              const int* __restrict__ rowstart, int* __restrict__ cursor,
                                              int* __restrict__ csr_src) {
  int e = blockIdx.x * 256 + threadIdx.x;
  if (e < NE) {
    int d = dst[e];
    int p = atomicAdd(&cursor[d], 1);
    csr_src[rowstart[d] + p] = src[e];
  }
}

// ---------------- SGEMM: H = X @ W, epilogue scales row by dis[row] ----------------
// NC==128: writes slice-major Hs[slice][node][16], fp32 (slice = col>>4).
// NC==32 : writes row-major fp32 [node][32].

template <int NC>
__global__ __launch_bounds__(256) void k_gemm(const float* __restrict__ X, const float* __restrict__ W,
                                              const float* __restrict__ dis, float* __restrict__ Hout, int M) {
  constexpr int TN = NC / 16;
  __shared__ float As[8][128];
  __shared__ float Bs[8][NC];
  const int tid = threadIdx.x;
  const int rg = tid >> 4;   // 0..15
  const int cg = tid & 15;   // 0..15
  const int row0 = blockIdx.x * 128;

  float acc[8][TN];
  #pragma unroll
  for (int i = 0; i < 8; i++)
    #pragma unroll
    for (int j = 0; j < TN; j++) acc[i][j] = 0.f;

  const int lr = tid >> 1;         // 0..127 row in tile
  const int lk = (tid & 1) * 4;    // 0 or 4

  for (int kt = 0; kt < 128; kt += 8) {
    float4 av = make_float4(0.f, 0.f, 0.f, 0.f);
    int gr = row0 + lr;
    if (gr < M) av = *(const float4*)(X + (size_t)gr * 128 + kt + lk);
    As[lk + 0][lr] = av.x; As[lk + 1][lr] = av.y; As[lk + 2][lr] = av.z; As[lk + 3][lr] = av.w;
    if constexpr (NC == 128) {
      int k = tid >> 5, c = (tid & 31) * 4;
      *(float4*)&Bs[k][c] = *(const float4*)(W + (size_t)(k + kt) * 128 + c);
    } else {  // NC == 32
      int k = tid >> 5, c = tid & 31;
      Bs[k][c] = W[(size_t)(k + kt) * NC + c];
    }
    __syncthreads();
    #pragma unroll
    for (int kk = 0; kk < 8; kk++) {
      float a[8];
      *(float4*)&a[0] = *(const float4*)&As[kk][rg * 8];
      *(float4*)&a[4] = *(const float4*)&As[kk][rg * 8 + 4];
      float b[TN];
      if constexpr (TN == 8) {
        *(float4*)&b[0] = *(const float4*)&Bs[kk][cg * 8];
        *(float4*)&b[4] = *(const float4*)&Bs[kk][cg * 8 + 4];
      } else {
        b[0] = Bs[kk][cg * 2]; b[1] = Bs[kk][cg * 2 + 1];
      }
      #pragma unroll
      for (int i = 0; i < 8; i++)
        #pragma unroll
        for (int j = 0; j < TN; j++) acc[i][j] += a[i] * b[j];
    }
    __syncthreads();
  }

  #pragma unroll
  for (int i = 0; i < 8; i++) {
    int gr = row0 + rg * 8 + i;
    if (gr < M) {
      float d = dis[gr];
      if constexpr (TN == 8) {
        // columns cg*8 .. cg*8+7 -> slice = cg>>1, within-slice col = (cg&1)*8
        size_t sbase = (size_t)(cg >> 1) * ((size_t)NN * 16) + (size_t)gr * 16 + (cg & 1) * 8;
        *(float4*)(Hout + sbase)     = make_float4(acc[i][0] * d, acc[i][1] * d, acc[i][2] * d, acc[i][3] * d);
        *(float4*)(Hout + sbase + 4) = make_float4(acc[i][4] * d, acc[i][5] * d, acc[i][6] * d, acc[i][7] * d);
      } else {
        *(float2*)(Hout + (size_t)gr * NC + cg * 2) = make_float2(acc[i][0] * d, acc[i][1] * d);
      }
    }
  }
}

// ---------------- aggregation, layer 0/1: XCD-sliced, shuffle-free, 8-wide MLP ----------
// slice = blockIdx & 7 (round-robin -> XCD); slice-major Hs: 3.2 MB resident/XCD.
// Wave = 8 nodes x 8 feature-lanes; each lane walks its node's CSR row with
// 8 independent gathers in flight. No cross-lane ops.
//   out = (sum Hs[src] + Hs[w]) * dis[w] + bias.

__global__ __launch_bounds__(256) void k_agg128(const float* __restrict__ Hs,
                                                const float* __restrict__ dis,
                                                const int* __restrict__ rowstart,
                                                const int* __restrict__ csr_src,
                                                const float* __restrict__ bias,
                                                float* __restrict__ out) {
  int slice = blockIdx.x & 7;
  int lane = threadIdx.x & 63;
  int node_sub = lane >> 3;      // 0..7: which node within the wave
  int fl = lane & 7;             // 0..7: feature pair within the slice
  int w = (blockIdx.x >> 3) * 32 + (threadIdx.x >> 6) * 8 + node_sub;
  if (w >= NN) return;           // per-lane guard; no cross-lane ops below
  const float* __restrict__ S = Hs + (size_t)slice * ((size_t)NN * 16) + fl * 2;
  float di = dis[w];
  int e0 = rowstart[w], e1 = rowstart[w + 1];
  float ax = 0.f, ay = 0.f;
  int e = e0;
  for (; e + 8 <= e1; e += 8) {
    int s0 = csr_src[e + 0], s1 = csr_src[e + 1], s2 = csr_src[e + 2], s3 = csr_src[e + 3];
    int s4 = csr_src[e + 4], s5 = csr_src[e + 5], s6 = csr_src[e + 6], s7 = csr_src[e + 7];
    float2 g0 = *(const float2*)(S + (size_t)s0 * 16);
    float2 g1 = *(const float2*)(S + (size_t)s1 * 16);
    float2 g2 = *(const float2*)(S + (size_t)s2 * 16);
    float2 g3 = *(const float2*)(S + (size_t)s3 * 16);
    float2 g4 = *(const float2*)(S + (size_t)s4 * 16);
    float2 g5 = *(const float2*)(S + (size_t)s5 * 16);
    float2 g6 = *(const float2*)(S + (size_t)s6 * 16);
    float2 g7 = *(const float2*)(S + (size_t)s7 * 16);
    ax += ((g0.x + g1.x) + (g2.x + g3.x)) + ((g4.x + g5.x) + (g6.x + g7.x));
    ay += ((g0.y + g1.y) + (g2.y + g3.y)) + ((g4.y + g5.y) + (g6.y + g7.y));
  }
  for (; e + 2 <= e1; e += 2) {
    int s0 = csr_src[e], s1 = csr_src[e + 1];
    float2 g0 = *(const float2*)(S + (size_t)s0 * 16);
    float2 g1 = *(const float2*)(S + (size_t)s1 * 16);
    ax += g0.x + g1.x;
    ay += g0.y + g1.y;
  }
  if (e < e1) {
    int s = csr_src[e];
    float2 g = *(const float2*)(S + (size_t)s * 16);
    ax += g.x;
    ay += g.y;
  }
  float2 selfv = *(const float2*)(S + (size_t)w * 16);
  int colOff = slice * 16 + fl * 2;
  float ox = (ax + selfv.x) * di + bias[colOff];
  float oy = (ay + selfv.y) * di + bias[colOff + 1];
  *(float2*)(out + (size_t)w * 128 + colOff) = make_float2(ox, oy);
}

// ---------------- final layer: aggregation + fused log_softmax ----------------
// Wave = 2 nodes x 32 lanes; lane owns one class column, walks its node's row
// with 8 gathers in flight; then max/sum reductions within each 32-lane half
// (xor masks <=16 never cross the half boundary).

__global__ __launch_bounds__(256) void k_agg32lsm(const float* __restrict__ H2,
                                                  const float* __restrict__ dis,
                                                  const int* __restrict__ rowstart,
                                                  const int* __restrict__ csr_src,
                                                  const float* __restrict__ bias,
                                                  float* __restrict__ out) {
  int wave = (blockIdx.x * 256 + threadIdx.x) >> 6;
  int lane = threadIdx.x & 63;
  int half = lane >> 5;
  int l = lane & 31;
  int w = wave * 2 + half;
  if (w >= NN) return;   // NN even: both halves of a wave exit together
  const float* __restrict__ S = H2 + l;
  float di = dis[w];
  int e0 = rowstart[w], e1 = rowstart[w + 1];
  float acc = 0.f;
  int e = e0;
  for (; e + 8 <= e1; e += 8) {
    int s0 = csr_src[e + 0], s1 = csr_src[e + 1], s2 = csr_src[e + 2], s3 = csr_src[e + 3];
    int s4 = csr_src[e + 4], s5 = csr_src[e + 5], s6 = csr_src[e + 6], s7 = csr_src[e + 7];
    float h0 = S[(size_t)s0 * 32], h1 = S[(size_t)s1 * 32], h2 = S[(size_t)s2 * 32], h3 = S[(size_t)s3 * 32];
    float h4 = S[(size_t)s4 * 32], h5 = S[(size_t)s5 * 32], h6 = S[(size_t)s6 * 32], h7 = S[(size_t)s7 * 32];
    acc += ((h0 + h1) + (h2 + h3)) + ((h4 + h5) + (h6 + h7));
  }
  for (; e + 2 <= e1; e += 2) {
    int s0 = csr_src[e], s1 = csr_src[e + 1];
    acc += S[(size_t)s0 * 32] + S[(size_t)s1 * 32];
  }
  if (e < e1) {
    acc += S[(size_t)csr_src[e] * 32];
  }
  float v = (acc + S[(size_t)w * 32]) * di + bias[l];
  // log_softmax within each 32-lane half
  float m = v;
  #pragma unroll
  for (int off = 16; off >= 1; off >>= 1) m = fmaxf(m, __shfl_xor(m, off));
  float ex = expf(v - m);
  float s = ex;
  #pragma unroll
  for (int off = 16; off >= 1; off >>= 1) s += __shfl_xor(s, off);
  out[(size_t)w * 32 + l] = v - m - logf(s);
}

// ---------------- BatchNorm stats + fused BN/ReLU/residual ----------------

__global__ __launch_bounds__(256) void k_bnstats(const float* __restrict__ O, float* __restrict__ gsum,
                                                 float* __restrict__ gsumsq) {
  int tid = threadIdx.x;
  int f = tid & 127;
  int half = tid >> 7;
  float s = 0.f, sq = 0.f;
  for (int r = blockIdx.x * 2 + half; r < NN; r += gridDim.x * 2) {
    float v = O[(size_t)r * 128 + f];
    s += v; sq += v * v;
  }
  __shared__ float sm[256], sm2[256];
  sm[tid] = s; sm2[tid] = sq;
  __syncthreads();
  if (tid < 128) {
    atomicAdd(&gsum[f], sm[tid] + sm[tid + 128]);
    atomicAdd(&gsumsq[f], sm2[tid] + sm2[tid + 128]);
  }
}

__global__ void k_bnfinal(const float* __restrict__ gsum, const float* __restrict__ gsumsq,
                          float* __restrict__ mu, float* __restrict__ istd) {
  int f = threadIdx.x;  // 128
  float m = gsum[f] / (float)NN;
  float v = gsumsq[f] / (float)NN - m * m;
  mu[f] = m;
  istd[f] = rsqrtf(v + 1e-5f);
}

__global__ __launch_bounds__(256) void k_fuse(const float* __restrict__ O, const float* Xin, float* Xout,
                                              const float* __restrict__ mu, const float* __restrict__ istd,
                                              const float* __restrict__ g, const float* __restrict__ be) {
  int i = blockIdx.x * 256 + threadIdx.x;
  if (i >= NN * 128 / 4) return;
  int f = (i * 4) & 127;
  float4 ov = ((const float4*)O)[i];
  float4 xv = ((const float4*)Xin)[i];
  float4 r;
  r.x = fmaxf((ov.x - mu[f + 0]) * istd[f + 0] * g[f + 0] + be[f + 0], 0.f) + xv.x;
  r.y = fmaxf((ov.y - mu[f + 1]) * istd[f + 1] * g[f + 1] + be[f + 1], 0.f) + xv.y;
  r.z = fmaxf((ov.z - mu[f + 2]) * istd[f + 2] * g[f + 2] + be[f + 2], 0.f) + xv.z;
  r.w = fmaxf((ov.w - mu[f + 3]) * istd[f + 3] * g[f + 3] + be[f + 3], 0.f) + xv.w;
  ((float4*)Xout)[i] = r;
}

// ---------------- launch ----------------

extern "C" void kernel_launch(void* const* d_in, const int* in_sizes, int n_in,
                              void* d_out, int out_size, void* d_ws, size_t ws_size,
                              hipStream_t stream) {
  const float* x   = (const float*)d_in[0];
  const int*   ei  = (const int*)d_in[1];
  const float* W0  = (const float*)d_in[2];
  const float* b0  = (const float*)d_in[3];
  const float* g0  = (const float*)d_in[4];
  const float* be0 = (const float*)d_in[5];
  const float* W1  = (const float*)d_in[6];
  const float* b1  = (const float*)d_in[7];
  const float* g1  = (const float*)d_in[8];
  const float* be1 = (const float*)d_in[9];
  const float* W2  = (const float*)d_in[10];
  const float* b2  = (const float*)d_in[11];
  float* out = (float*)d_out;
  const int* srcI = ei;
  const int* dstI = ei + NE;

  char* p = (char*)d_ws;
  auto take = [&](size_t bytes) { char* r = p; p += (bytes + 255) & ~(size_t)255; return (void*)r; };
  int*   deg      = (int*)take(NN * 4);
  int*   cursor   = (int*)take(NN * 4);
  int*   rowstart = (int*)take((NN + 1) * 4);
  int*   blksum   = (int*)take(64 * 4);
  int*   blkoff   = (int*)take(64 * 4);
  float* dis      = (float*)take(NN * 4);
  int*   csr      = (int*)take(NE * 4);
  float* gstat    = (float*)take(256 * 4);
  float* mu       = (float*)take(128 * 4);
  float* istd     = (float*)take(128 * 4);
  float* hs       = (float*)take((size_t)NN * 128 * 4);  // fp32, slice-major, pre-scaled
  float* o        = (float*)take((size_t)NN * 128 * 4);
  float* xA       = (float*)take((size_t)NN * 128 * 4);
  float* h2       = (float*)take((size_t)NN * 32 * 4);

  hipMemsetAsync(deg, 0, NN * 4, stream);
  hipMemsetAsync(cursor, 0, NN * 4, stream);

  k_deg<<<(NE + 255) / 256, 256, 0, stream>>>(dstI, deg);
  k_scan1<<<NBLK, 1024, 0, stream>>>(deg, rowstart, blksum);
  k_scan2<<<1, 64, 0, stream>>>(blksum, blkoff, rowstart);
  k_scan3<<<(NN + 255) / 256, 256, 0, stream>>>(rowstart, blkoff, deg, dis);
  k_fill<<<(NE + 255) / 256, 256, 0, stream>>>(srcI, dstI, rowstart, cursor, csr);

  const int aggGrid = ((NN + 31) / 32) * 8;  // 32 nodes/block x 8 slices

  // ---- layer 0 ----
  k_gemm<128><<<(NN + 127) / 128, 256, 0, stream>>>(x, W0, dis, hs, NN);
  k_agg128<<<aggGrid, 256, 0, stream>>>(hs, dis, rowstart, csr, b0, o);
  hipMemsetAsync(gstat, 0, 256 * 4, stream);
  k_bnstats<<<256, 256, 0, stream>>>(o, gstat, gstat + 128);
  k_bnfinal<<<1, 128, 0, stream>>>(gstat, gstat + 128, mu, istd);
  k_fuse<<<(NN * 128 / 4 + 255) / 256, 256, 0, stream>>>(o, x, xA, mu, istd, g0, be0);

  // ---- layer 1 ----
  k_gemm<128><<<(NN + 127) / 128, 256, 0, stream>>>(xA, W1, dis, hs, NN);
  k_agg128<<<aggGrid, 256, 0, stream>>>(hs, dis, rowstart, csr, b1, o);
  hipMemsetAsync(gstat, 0, 256 * 4, stream);
  k_bnstats<<<256, 256, 0, stream>>>(o, gstat, gstat + 128);
  k_bnfinal<<<1, 128, 0, stream>>>(gstat, gstat + 128, mu, istd);
  k_fuse<<<(NN * 128 / 4 + 255) / 256, 256, 0, stream>>>(o, xA, xA, mu, istd, g1, be1);

  // ---- final conv + fused aggregation/log_softmax ----
  k_gemm<32><<<(NN + 127) / 128, 256, 0, stream>>>(xA, W2, dis, h2, NN);
  k_agg32lsm<<<(NN + 7) / 8, 256, 0, stream>>>(h2, dis, rowstart, csr, b2, out);
}

// Round 7
// 474.112 us; speedup vs baseline: 1.0874x; 1.0486x over previous
//
#include <hip/hip_runtime.h>
#include <math.h>

#define NN 50000
#define NNP (NN + 1)          // +1 dummy zero row per slice
#define NE 800000
#define NEP 1150000           // NE + 7*NN upper bound on padded edge count
#define NBLK 49               // ceil(NN/1024)

// ---------------- degree / CSR build (rows padded to multiple of 8) ----------------

__global__ __launch_bounds__(256) void k_deg(const int* __restrict__ dst, int* __restrict__ deg) {
  int e = blockIdx.x * 256 + threadIdx.x;
  if (e < NE) atomicAdd(&deg[dst[e]], 1);
}

__global__ __launch_bounds__(256) void k_prefill(int* __restrict__ csr) {
  int i = blockIdx.x * 256 + threadIdx.x;
  if (i < NEP) csr[i] = NN;   // dummy node -> zero row
}

// scan PADDED degrees
__global__ __launch_bounds__(1024) void k_scan1(const int* __restrict__ deg, int* __restrict__ excl,
                                                int* __restrict__ blksum) {
  __shared__ int sm[1024];
  int t = threadIdx.x;
  int i = blockIdx.x * 1024 + t;
  int v = (i < NN) ? ((deg[i] + 7) & ~7) : 0;
  sm[t] = v;
  __syncthreads();
  for (int off = 1; off < 1024; off <<= 1) {
    int x = (t >= off) ? sm[t - off] : 0;
    __syncthreads();
    sm[t] += x;
    __syncthreads();
  }
  if (i < NN) excl[i] = sm[t] - v;
  if (t == 1023) blksum[blockIdx.x] = sm[t];
}

__global__ void k_scan2(const int* __restrict__ blksum, int* __restrict__ blkoff,
                        int* __restrict__ rowstart) {
  int t = threadIdx.x;  // 64 threads, one wave
  int orig = (t < NBLK) ? blksum[t] : 0;
  int v = orig;
  #pragma unroll
  for (int off = 1; off < 64; off <<= 1) {
    int u = __shfl_up(v, off);
    if (t >= off) v += u;
  }
  if (t < NBLK) blkoff[t] = v - orig;
  if (t == NBLK - 1) rowstart[NN] = v;  // padded edge total
}

// also computes dis[] from TRUE degree
__global__ __launch_bounds__(256) void k_scan3(int* __restrict__ excl, const int* __restrict__ blkoff,
                                               const int* __restrict__ deg, float* __restrict__ dis) {
  int i = blockIdx.x * 256 + threadIdx.x;
  if (i < NN) {
    excl[i] += blkoff[i >> 10];
    dis[i] = rsqrtf((float)deg[i] + 1.0f);
  }
}

__global__ __launch_bounds__(256) void k_fill(const int* __restrict__ src, const int* __restrict__ dst,
                                              const int* __restrict__ rowstart, int* __restrict__ cursor,
                                              int* __restrict__ csr_src) {
  int e = blockIdx.x * 256 + threadIdx.x;
  if (e < NE) {
    int d = dst[e];
    int p = atomicAdd(&cursor[d], 1);
    csr_src[rowstart[d] + p] = src[e];
  }
}

// zero the dummy rows: Hs row NN of each slice (16 floats x 8) + h2 row NN (32 floats)
__global__ void k_zeropad(float* __restrict__ hs, float* __restrict__ h2) {
  int t = threadIdx.x;  // 256
  if (t < 128) {
    int slice = t >> 4, c = t & 15;
    hs[(size_t)slice * ((size_t)NNP * 16) + (size_t)NN * 16 + c] = 0.f;
  } else if (t < 160) {
    h2[(size_t)NN * 32 + (t - 128)] = 0.f;
  }
}

// ---------------- SGEMM 128->128: 64-row tiles, micro 4x8, slice-major out ----------------
// Hs[slice][node][16] fp32, pre-scaled by dis[row]; slice stride NNP rows.

__global__ __launch_bounds__(256) void k_gemm128(const float* __restrict__ X, const float* __restrict__ W,
                                                 const float* __restrict__ dis, float* __restrict__ Hs, int M) {
  __shared__ float As[8][64];
  __shared__ float Bs[8][128];
  const int tid = threadIdx.x;
  const int rg = tid >> 4;   // 0..15: 4-row group
  const int cg = tid & 15;   // 0..15: 8-col group
  const int row0 = blockIdx.x * 64;

  float acc[4][8];
  #pragma unroll
  for (int i = 0; i < 4; i++)
    #pragma unroll
    for (int j = 0; j < 8; j++) acc[i][j] = 0.f;

  const int lr = tid >> 2;        // 0..63
  const int lk = (tid & 3) * 2;   // 0,2,4,6

  for (int kt = 0; kt < 128; kt += 8) {
    float2 av = make_float2(0.f, 0.f);
    int gr = row0 + lr;
    if (gr < M) av = *(const float2*)(X + (size_t)gr * 128 + kt + lk);
    As[lk][lr] = av.x; As[lk + 1][lr] = av.y;
    int k = tid >> 5, c = (tid & 31) * 4;
    *(float4*)&Bs[k][c] = *(const float4*)(W + (size_t)(k + kt) * 128 + c);
    __syncthreads();
    #pragma unroll
    for (int kk = 0; kk < 8; kk++) {
      float a[4], b[8];
      *(float4*)&a[0] = *(const float4*)&As[kk][rg * 4];
      *(float4*)&b[0] = *(const float4*)&Bs[kk][cg * 8];
      *(float4*)&b[4] = *(const float4*)&Bs[kk][cg * 8 + 4];
      #pragma unroll
      for (int i = 0; i < 4; i++)
        #pragma unroll
        for (int j = 0; j < 8; j++) acc[i][j] += a[i] * b[j];
    }
    __syncthreads();
  }

  #pragma unroll
  for (int i = 0; i < 4; i++) {
    int gr = row0 + rg * 4 + i;
    if (gr < M) {
      float d = dis[gr];
      size_t sbase = (size_t)(cg >> 1) * ((size_t)NNP * 16) + (size_t)gr * 16 + (cg & 1) * 8;
      *(float4*)(Hs + sbase)     = make_float4(acc[i][0] * d, acc[i][1] * d, acc[i][2] * d, acc[i][3] * d);
      *(float4*)(Hs + sbase + 4) = make_float4(acc[i][4] * d, acc[i][5] * d, acc[i][6] * d, acc[i][7] * d);
    }
  }
}

// ---------------- SGEMM 128->32: 128-row tiles, micro 8x2, row-major out ----------------

__global__ __launch_bounds__(256) void k_gemm32(const float* __restrict__ X, const float* __restrict__ W,
                                                const float* __restrict__ dis, float* __restrict__ H, int M) {
  __shared__ float As[8][128];
  __shared__ float Bs[8][32];
  const int tid = threadIdx.x;
  const int rg = tid >> 4;
  const int cg = tid & 15;
  const int row0 = blockIdx.x * 128;

  float acc[8][2];
  #pragma unroll
  for (int i = 0; i < 8; i++) { acc[i][0] = 0.f; acc[i][1] = 0.f; }

  const int lr = tid >> 1;
  const int lk = (tid & 1) * 4;

  for (int kt = 0; kt < 128; kt += 8) {
    float4 av = make_float4(0.f, 0.f, 0.f, 0.f);
    int gr = row0 + lr;
    if (gr < M) av = *(const float4*)(X + (size_t)gr * 128 + kt + lk);
    As[lk + 0][lr] = av.x; As[lk + 1][lr] = av.y; As[lk + 2][lr] = av.z; As[lk + 3][lr] = av.w;
    int k = tid >> 5, c = tid & 31;
    Bs[k][c] = W[(size_t)(k + kt) * 32 + c];
    __syncthreads();
    #pragma unroll
    for (int kk = 0; kk < 8; kk++) {
      float a[8];
      *(float4*)&a[0] = *(const float4*)&As[kk][rg * 8];
      *(float4*)&a[4] = *(const float4*)&As[kk][rg * 8 + 4];
      float b0 = Bs[kk][cg * 2], b1 = Bs[kk][cg * 2 + 1];
      #pragma unroll
      for (int i = 0; i < 8; i++) { acc[i][0] += a[i] * b0; acc[i][1] += a[i] * b1; }
    }
    __syncthreads();
  }

  #pragma unroll
  for (int i = 0; i < 8; i++) {
    int gr = row0 + rg * 8 + i;
    if (gr < M) {
      float d = dis[gr];
      *(float2*)(H + (size_t)gr * 32 + cg * 2) = make_float2(acc[i][0] * d, acc[i][1] * d);
    }
  }
}

// ---------------- aggregation, layer 0/1 ----------------
// Wave = 8 nodes x 8 feature-lanes, slice = blockIdx & 7 (XCD round-robin).
// Rows padded to x8 with dummy node NN (zero row): uniform 8-wide iterations.
// One cooperative index load + 8 in-group shuffles + 8 independent gathers.

__global__ __launch_bounds__(256) void k_agg128(const float* __restrict__ Hs,
                                                const float* __restrict__ dis,
                                                const int* __restrict__ rowstart,
                                                const int* __restrict__ csr_src,
                                                const float* __restrict__ bias,
                                                float* __restrict__ out) {
  int slice = blockIdx.x & 7;
  int lane = threadIdx.x & 63;
  int node_sub = lane >> 3;      // 0..7
  int fl = lane & 7;             // 0..7 (feature pair)
  int base = node_sub * 8;
  int w = (blockIdx.x >> 3) * 32 + (threadIdx.x >> 6) * 8 + node_sub;
  if (w >= NN) return;
  const float* __restrict__ S = Hs + (size_t)slice * ((size_t)NNP * 16) + fl * 2;
  float di = dis[w];
  int e0 = rowstart[w], e1 = rowstart[w + 1];   // padded bounds
  float ax = 0.f, ay = 0.f;
  for (int e = e0; e < e1; e += 8) {
    int myIdx = csr_src[e + fl];               // one instr: 64 indices
    int s0 = __shfl(myIdx, base + 0), s1 = __shfl(myIdx, base + 1);
    int s2 = __shfl(myIdx, base + 2), s3 = __shfl(myIdx, base + 3);
    int s4 = __shfl(myIdx, base + 4), s5 = __shfl(myIdx, base + 5);
    int s6 = __shfl(myIdx, base + 6), s7 = __shfl(myIdx, base + 7);
    float2 g0 = *(const float2*)(S + (size_t)s0 * 16);
    float2 g1 = *(const float2*)(S + (size_t)s1 * 16);
    float2 g2 = *(const float2*)(S + (size_t)s2 * 16);
    float2 g3 = *(const float2*)(S + (size_t)s3 * 16);
    float2 g4 = *(const float2*)(S + (size_t)s4 * 16);
    float2 g5 = *(const float2*)(S + (size_t)s5 * 16);
    float2 g6 = *(const float2*)(S + (size_t)s6 * 16);
    float2 g7 = *(const float2*)(S + (size_t)s7 * 16);
    ax += ((g0.x + g1.x) + (g2.x + g3.x)) + ((g4.x + g5.x) + (g6.x + g7.x));
    ay += ((g0.y + g1.y) + (g2.y + g3.y)) + ((g4.y + g5.y) + (g6.y + g7.y));
  }
  float2 selfv = *(const float2*)(S + (size_t)w * 16);
  int colOff = slice * 16 + fl * 2;
  float ox = (ax + selfv.x) * di + bias[colOff];
  float oy = (ay + selfv.y) * di + bias[colOff + 1];
  *(float2*)(out + (size_t)w * 128 + colOff) = make_float2(ox, oy);
}

// ---------------- final layer: aggregation + fused log_softmax ----------------
// Wave = 2 nodes x 32 lanes; padded rows, dummy zero row NN in H2.

__global__ __launch_bounds__(256) void k_agg32lsm(const float* __restrict__ H2,
                                                  const float* __restrict__ dis,
                                                  const int* __restrict__ rowstart,
                                                  const int* __restrict__ csr_src,
                                                  const float* __restrict__ bias,
                                                  float* __restrict__ out) {
  int wave = (blockIdx.x * 256 + threadIdx.x) >> 6;
  int lane = threadIdx.x & 63;
  int half = lane >> 5;
  int l = lane & 31;
  int hbase = half * 32;
  int w = wave * 2 + half;
  if (w >= NN) return;   // NN even: both halves exit together
  const float* __restrict__ S = H2 + l;
  float di = dis[w];
  int e0 = rowstart[w], e1 = rowstart[w + 1];
  float acc = 0.f;
  for (int e = e0; e < e1; e += 8) {
    int myIdx = csr_src[e + (l & 7)];
    int s0 = __shfl(myIdx, hbase + 0), s1 = __shfl(myIdx, hbase + 1);
    int s2 = __shfl(myIdx, hbase + 2), s3 = __shfl(myIdx, hbase + 3);
    int s4 = __shfl(myIdx, hbase + 4), s5 = __shfl(myIdx, hbase + 5);
    int s6 = __shfl(myIdx, hbase + 6), s7 = __shfl(myIdx, hbase + 7);
    float h0 = S[(size_t)s0 * 32], h1 = S[(size_t)s1 * 32];
    float h2v = S[(size_t)s2 * 32], h3 = S[(size_t)s3 * 32];
    float h4 = S[(size_t)s4 * 32], h5 = S[(size_t)s5 * 32];
    float h6 = S[(size_t)s6 * 32], h7 = S[(size_t)s7 * 32];
    acc += ((h0 + h1) + (h2v + h3)) + ((h4 + h5) + (h6 + h7));
  }
  float v = (acc + S[(size_t)w * 32]) * di + bias[l];
  float m = v;
  #pragma unroll
  for (int off = 16; off >= 1; off >>= 1) m = fmaxf(m, __shfl_xor(m, off));
  float ex = expf(v - m);
  float s = ex;
  #pragma unroll
  for (int off = 16; off >= 1; off >>= 1) s += __shfl_xor(s, off);
  out[(size_t)w * 32 + l] = v - m - logf(s);
}

// ---------------- BatchNorm stats + fused BN/ReLU/residual ----------------

__global__ __launch_bounds__(256) void k_bnstats(const float* __restrict__ O, float* __restrict__ gsum,
                                                 float* __restrict__ gsumsq) {
  int tid = threadIdx.x;
  int f = tid & 127;
  int half = tid >> 7;
  float s = 0.f, sq = 0.f;
  for (int r = blockIdx.x * 2 + half; r < NN; r += gridDim.x * 2) {
    float v = O[(size_t)r * 128 + f];
    s += v; sq += v * v;
  }
  __shared__ float sm[256], sm2[256];
  sm[tid] = s; sm2[tid] = sq;
  __syncthreads();
  if (tid < 128) {
    atomicAdd(&gsum[f], sm[tid] + sm[tid + 128]);
    atomicAdd(&gsumsq[f], sm2[tid] + sm2[tid + 128]);
  }
}

__global__ void k_bnfinal(const float* __restrict__ gsum, const float* __restrict__ gsumsq,
                          float* __restrict__ mu, float* __restrict__ istd) {
  int f = threadIdx.x;  // 128
  float m = gsum[f] / (float)NN;
  float v = gsumsq[f] / (float)NN - m * m;
  mu[f] = m;
  istd[f] = rsqrtf(v + 1e-5f);
}

__global__ __launch_bounds__(256) void k_fuse(const float* __restrict__ O, const float* Xin, float* Xout,
                                              const float* __restrict__ mu, const float* __restrict__ istd,
                                              const float* __restrict__ g, const float* __restrict__ be) {
  int i = blockIdx.x * 256 + threadIdx.x;
  if (i >= NN * 128 / 4) return;
  int f = (i * 4) & 127;
  float4 ov = ((const float4*)O)[i];
  float4 xv = ((const float4*)Xin)[i];
  float4 r;
  r.x = fmaxf((ov.x - mu[f + 0]) * istd[f + 0] * g[f + 0] + be[f + 0], 0.f) + xv.x;
  r.y = fmaxf((ov.y - mu[f + 1]) * istd[f + 1] * g[f + 1] + be[f + 1], 0.f) + xv.y;
  r.z = fmaxf((ov.z - mu[f + 2]) * istd[f + 2] * g[f + 2] + be[f + 2], 0.f) + xv.z;
  r.w = fmaxf((ov.w - mu[f + 3]) * istd[f + 3] * g[f + 3] + be[f + 3], 0.f) + xv.w;
  ((float4*)Xout)[i] = r;
}

// ---------------- launch ----------------

extern "C" void kernel_launch(void* const* d_in, const int* in_sizes, int n_in,
                              void* d_out, int out_size, void* d_ws, size_t ws_size,
                              hipStream_t stream) {
  const float* x   = (const float*)d_in[0];
  const int*   ei  = (const int*)d_in[1];
  const float* W0  = (const float*)d_in[2];
  const float* b0  = (const float*)d_in[3];
  const float* g0  = (const float*)d_in[4];
  const float* be0 = (const float*)d_in[5];
  const float* W1  = (const float*)d_in[6];
  const float* b1  = (const float*)d_in[7];
  const float* g1  = (const float*)d_in[8];
  const float* be1 = (const float*)d_in[9];
  const float* W2  = (const float*)d_in[10];
  const float* b2  = (const float*)d_in[11];
  float* out = (float*)d_out;
  const int* srcI = ei;
  const int* dstI = ei + NE;

  char* p = (char*)d_ws;
  auto take = [&](size_t bytes) { char* r = p; p += (bytes + 255) & ~(size_t)255; return (void*)r; };
  int*   deg      = (int*)take(NN * 4);
  int*   cursor   = (int*)take(NN * 4);
  int*   rowstart = (int*)take((NN + 1) * 4);
  int*   blksum   = (int*)take(64 * 4);
  int*   blkoff   = (int*)take(64 * 4);
  float* dis      = (float*)take(NN * 4);
  int*   csr      = (int*)take((size_t)NEP * 4);
  float* gstat    = (float*)take(256 * 4);
  float* mu       = (float*)take(128 * 4);
  float* istd     = (float*)take(128 * 4);
  float* hs       = (float*)take((size_t)NNP * 128 * 4);  // fp32, slice-major (stride NNP), pre-scaled
  float* o        = (float*)take((size_t)NN * 128 * 4);
  float* xA       = (float*)take((size_t)NN * 128 * 4);
  float* h2       = (float*)take((size_t)NNP * 32 * 4);

  hipMemsetAsync(deg, 0, NN * 4, stream);
  hipMemsetAsync(cursor, 0, NN * 4, stream);

  k_deg<<<(NE + 255) / 256, 256, 0, stream>>>(dstI, deg);
  k_prefill<<<(NEP + 255) / 256, 256, 0, stream>>>(csr);
  k_scan1<<<NBLK, 1024, 0, stream>>>(deg, rowstart, blksum);
  k_scan2<<<1, 64, 0, stream>>>(blksum, blkoff, rowstart);
  k_scan3<<<(NN + 255) / 256, 256, 0, stream>>>(rowstart, blkoff, deg, dis);
  k_fill<<<(NE + 255) / 256, 256, 0, stream>>>(srcI, dstI, rowstart, cursor, csr);
  k_zeropad<<<1, 256, 0, stream>>>(hs, h2);

  const int aggGrid = ((NN + 31) / 32) * 8;  // 32 nodes/block x 8 slices

  // ---- layer 0 ----
  k_gemm128<<<(NN + 63) / 64, 256, 0, stream>>>(x, W0, dis, hs, NN);
  k_agg128<<<aggGrid, 256, 0, stream>>>(hs, dis, rowstart, csr, b0, o);
  hipMemsetAsync(gstat, 0, 256 * 4, stream);
  k_bnstats<<<1024, 256, 0, stream>>>(o, gstat, gstat + 128);
  k_bnfinal<<<1, 128, 0, stream>>>(gstat, gstat + 128, mu, istd);
  k_fuse<<<(NN * 128 / 4 + 255) / 256, 256, 0, stream>>>(o, x, xA, mu, istd, g0, be0);

  // ---- layer 1 ----
  k_gemm128<<<(NN + 63) / 64, 256, 0, stream>>>(xA, W1, dis, hs, NN);
  k_agg128<<<aggGrid, 256, 0, stream>>>(hs, dis, rowstart, csr, b1, o);
  hipMemsetAsync(gstat, 0, 256 * 4, stream);
  k_bnstats<<<1024, 256, 0, stream>>>(o, gstat, gstat + 128);
  k_bnfinal<<<1, 128, 0, stream>>>(gstat, gstat + 128, mu, istd);
  k_fuse<<<(NN * 128 / 4 + 255) / 256, 256, 0, stream>>>(o, xA, xA, mu, istd, g1, be1);

  // ---- final conv + fused aggregation/log_softmax ----
  k_gemm32<<<(NN + 127) / 128, 256, 0, stream>>>(xA, W2, dis, h2, NN);
  k_agg32lsm<<<(NN + 7) / 8, 256, 0, stream>>>(h2, dis, rowstart, csr, b2, out);
}

// Round 8
// 441.524 us; speedup vs baseline: 1.1677x; 1.0738x over previous
//
#include <hip/hip_runtime.h>
#include <math.h>

#define NN 50000
#define NNP (NN + 1)          // +1 dummy zero row per slice
#define NE 800000
#define NEP 1150000           // NE + 7*NN upper bound on padded edge count
#define NBLK 49               // ceil(NN/1024)

// ---------------- init: zero deg/cursor/gstat, prefill csr with dummy ----------------

__global__ __launch_bounds__(256) void k_init(int* __restrict__ deg, int* __restrict__ cursor,
                                              float* __restrict__ gstat, int* __restrict__ csr) {
  int i = blockIdx.x * 256 + threadIdx.x;
  if (i < NEP) csr[i] = NN;
  if (i < NN) { deg[i] = 0; cursor[i] = 0; }
  if (i < 512) gstat[i] = 0.f;
}

__global__ __launch_bounds__(256) void k_deg(const int* __restrict__ dst, int* __restrict__ deg) {
  int e = blockIdx.x * 256 + threadIdx.x;
  if (e < NE) atomicAdd(&deg[dst[e]], 1);
}

// scan PADDED degrees
__global__ __launch_bounds__(1024) void k_scan1(const int* __restrict__ deg, int* __restrict__ excl,
                                                int* __restrict__ blksum) {
  __shared__ int sm[1024];
  int t = threadIdx.x;
  int i = blockIdx.x * 1024 + t;
  int v = (i < NN) ? ((deg[i] + 7) & ~7) : 0;
  sm[t] = v;
  __syncthreads();
  for (int off = 1; off < 1024; off <<= 1) {
    int x = (t >= off) ? sm[t - off] : 0;
    __syncthreads();
    sm[t] += x;
    __syncthreads();
  }
  if (i < NN) excl[i] = sm[t] - v;
  if (t == 1023) blksum[blockIdx.x] = sm[t];
}

__global__ void k_scan2(const int* __restrict__ blksum, int* __restrict__ blkoff,
                        int* __restrict__ rowstart) {
  int t = threadIdx.x;  // 64 threads, one wave
  int orig = (t < NBLK) ? blksum[t] : 0;
  int v = orig;
  #pragma unroll
  for (int off = 1; off < 64; off <<= 1) {
    int u = __shfl_up(v, off);
    if (t >= off) v += u;
  }
  if (t < NBLK) blkoff[t] = v - orig;
  if (t == NBLK - 1) rowstart[NN] = v;  // padded edge total
}

// excl += blkoff; dis from TRUE degree; also zero the dummy pad rows of hs/h2
__global__ __launch_bounds__(256) void k_scan3(int* __restrict__ excl, const int* __restrict__ blkoff,
                                               const int* __restrict__ deg, float* __restrict__ dis,
                                               float* __restrict__ hs, float* __restrict__ h2) {
  int i = blockIdx.x * 256 + threadIdx.x;
  if (i < NN) {
    excl[i] += blkoff[i >> 10];
    dis[i] = rsqrtf((float)deg[i] + 1.0f);
  }
  if (i < 128) {   // hs pad row: 4 slices x 32 floats
    int slice = i >> 5, c = i & 31;
    hs[(size_t)slice * ((size_t)NNP * 32) + (size_t)NN * 32 + c] = 0.f;
  }
  if (i < 32) h2[(size_t)NN * 32 + i] = 0.f;
}

__global__ __launch_bounds__(256) void k_fill(const int* __restrict__ src, const int* __restrict__ dst,
                                              const int* __restrict__ rowstart, int* __restrict__ cursor,
                                              int* __restrict__ csr_src) {
  int e = blockIdx.x * 256 + threadIdx.x;
  if (e < NE) {
    int d = dst[e];
    int p = atomicAdd(&cursor[d], 1);
    csr_src[rowstart[d] + p] = src[e];
  }
}

// ---------------- SGEMM 128->128: 64-row tiles, micro 4x8, 4-slice-major out ----------------
// Hs[slice][node][32] fp32 (slice = col>>5, stride NNP rows), pre-scaled by dis[row].

__global__ __launch_bounds__(256) void k_gemm128(const float* __restrict__ X, const float* __restrict__ W,
                                                 const float* __restrict__ dis, float* __restrict__ Hs, int M) {
  __shared__ float As[8][64];
  __shared__ float Bs[8][128];
  const int tid = threadIdx.x;
  const int rg = tid >> 4;   // 0..15: 4-row group
  const int cg = tid & 15;   // 0..15: 8-col group
  const int row0 = blockIdx.x * 64;

  float acc[4][8];
  #pragma unroll
  for (int i = 0; i < 4; i++)
    #pragma unroll
    for (int j = 0; j < 8; j++) acc[i][j] = 0.f;

  const int lr = tid >> 2;        // 0..63
  const int lk = (tid & 3) * 2;   // 0,2,4,6

  for (int kt = 0; kt < 128; kt += 8) {
    float2 av = make_float2(0.f, 0.f);
    int gr = row0 + lr;
    if (gr < M) av = *(const float2*)(X + (size_t)gr * 128 + kt + lk);
    As[lk][lr] = av.x; As[lk + 1][lr] = av.y;
    int k = tid >> 5, c = (tid & 31) * 4;
    *(float4*)&Bs[k][c] = *(const float4*)(W + (size_t)(k + kt) * 128 + c);
    __syncthreads();
    #pragma unroll
    for (int kk = 0; kk < 8; kk++) {
      float a[4], b[8];
      *(float4*)&a[0] = *(const float4*)&As[kk][rg * 4];
      *(float4*)&b[0] = *(const float4*)&Bs[kk][cg * 8];
      *(float4*)&b[4] = *(const float4*)&Bs[kk][cg * 8 + 4];
      #pragma unroll
      for (int i = 0; i < 4; i++)
        #pragma unroll
        for (int j = 0; j < 8; j++) acc[i][j] += a[i] * b[j];
    }
    __syncthreads();
  }

  #pragma unroll
  for (int i = 0; i < 4; i++) {
    int gr = row0 + rg * 4 + i;
    if (gr < M) {
      float d = dis[gr];
      // cols cg*8..cg*8+7 -> slice = cg>>2, within-slice offset = (cg&3)*8
      size_t sbase = (size_t)(cg >> 2) * ((size_t)NNP * 32) + (size_t)gr * 32 + (cg & 3) * 8;
      *(float4*)(Hs + sbase)     = make_float4(acc[i][0] * d, acc[i][1] * d, acc[i][2] * d, acc[i][3] * d);
      *(float4*)(Hs + sbase + 4) = make_float4(acc[i][4] * d, acc[i][5] * d, acc[i][6] * d, acc[i][7] * d);
    }
  }
}

// ---------------- SGEMM 128->32: 128-row tiles, micro 8x2, row-major out ----------------

__global__ __launch_bounds__(256) void k_gemm32(const float* __restrict__ X, const float* __restrict__ W,
                                                const float* __restrict__ dis, float* __restrict__ H, int M) {
  __shared__ float As[8][128];
  __shared__ float Bs[8][32];
  const int tid = threadIdx.x;
  const int rg = tid >> 4;
  const int cg = tid & 15;
  const int row0 = blockIdx.x * 128;

  float acc[8][2];
  #pragma unroll
  for (int i = 0; i < 8; i++) { acc[i][0] = 0.f; acc[i][1] = 0.f; }

  const int lr = tid >> 1;
  const int lk = (tid & 1) * 4;

  for (int kt = 0; kt < 128; kt += 8) {
    float4 av = make_float4(0.f, 0.f, 0.f, 0.f);
    int gr = row0 + lr;
    if (gr < M) av = *(const float4*)(X + (size_t)gr * 128 + kt + lk);
    As[lk + 0][lr] = av.x; As[lk + 1][lr] = av.y; As[lk + 2][lr] = av.z; As[lk + 3][lr] = av.w;
    int k = tid >> 5, c = tid & 31;
    Bs[k][c] = W[(size_t)(k + kt) * 32 + c];
    __syncthreads();
    #pragma unroll
    for (int kk = 0; kk < 8; kk++) {
      float a[8];
      *(float4*)&a[0] = *(const float4*)&As[kk][rg * 8];
      *(float4*)&a[4] = *(const float4*)&As[kk][rg * 8 + 4];
      float b0 = Bs[kk][cg * 2], b1 = Bs[kk][cg * 2 + 1];
      #pragma unroll
      for (int i = 0; i < 8; i++) { acc[i][0] += a[i] * b0; acc[i][1] += a[i] * b1; }
    }
    __syncthreads();
  }

  #pragma unroll
  for (int i = 0; i < 8; i++) {
    int gr = row0 + rg * 8 + i;
    if (gr < M) {
      float d = dis[gr];
      *(float2*)(H + (size_t)gr * 32 + cg * 2) = make_float2(acc[i][0] * d, acc[i][1] * d);
    }
  }
}

// ---------------- aggregation, layer 0/1 ----------------
// 4 slices x 32 features = 128 B rows: every gathered cache line is fully used.
// Wave = 8 nodes x 8 feature-lanes (float4 each). slice = blockIdx & 3; blockIdx
// round-robins XCDs so each slice lives on 2 XCDs (partial L2 residency).
// Rows padded to x8 with dummy node NN (zero row): uniform iterations, no remainder.

__global__ __launch_bounds__(256) void k_agg128(const float* __restrict__ Hs,
                                                const float* __restrict__ dis,
                                                const int* __restrict__ rowstart,
                                                const int* __restrict__ csr_src,
                                                const float* __restrict__ bias,
                                                float* __restrict__ out) {
  int slice = blockIdx.x & 3;
  int lane = threadIdx.x & 63;
  int node_sub = lane >> 3;      // 0..7
  int fl = lane & 7;             // 0..7 (float4 each)
  int base = node_sub * 8;
  int w = (blockIdx.x >> 2) * 32 + (threadIdx.x >> 6) * 8 + node_sub;
  if (w >= NN) return;
  const float* __restrict__ S = Hs + (size_t)slice * ((size_t)NNP * 32) + fl * 4;
  float di = dis[w];
  int e0 = rowstart[w], e1 = rowstart[w + 1];   // padded, group-uniform
  float4 acc = make_float4(0.f, 0.f, 0.f, 0.f);
  for (int e = e0; e < e1; e += 8) {
    int myIdx = csr_src[e + fl];               // one instr: 64 indices (8/node)
    int s0 = __shfl(myIdx, base + 0), s1 = __shfl(myIdx, base + 1);
    int s2 = __shfl(myIdx, base + 2), s3 = __shfl(myIdx, base + 3);
    int s4 = __shfl(myIdx, base + 4), s5 = __shfl(myIdx, base + 5);
    int s6 = __shfl(myIdx, base + 6), s7 = __shfl(myIdx, base + 7);
    float4 g0 = *(const float4*)(S + (size_t)s0 * 32);
    float4 g1 = *(const float4*)(S + (size_t)s1 * 32);
    float4 g2 = *(const float4*)(S + (size_t)s2 * 32);
    float4 g3 = *(const float4*)(S + (size_t)s3 * 32);
    float4 g4 = *(const float4*)(S + (size_t)s4 * 32);
    float4 g5 = *(const float4*)(S + (size_t)s5 * 32);
    float4 g6 = *(const float4*)(S + (size_t)s6 * 32);
    float4 g7 = *(const float4*)(S + (size_t)s7 * 32);
    acc.x += ((g0.x + g1.x) + (g2.x + g3.x)) + ((g4.x + g5.x) + (g6.x + g7.x));
    acc.y += ((g0.y + g1.y) + (g2.y + g3.y)) + ((g4.y + g5.y) + (g6.y + g7.y));
    acc.z += ((g0.z + g1.z) + (g2.z + g3.z)) + ((g4.z + g5.z) + (g6.z + g7.z));
    acc.w += ((g0.w + g1.w) + (g2.w + g3.w)) + ((g4.w + g5.w) + (g6.w + g7.w));
  }
  float4 selfv = *(const float4*)(S + (size_t)w * 32);
  int colOff = slice * 32 + fl * 4;
  float4 bv = *(const float4*)(bias + colOff);
  float4 r;
  r.x = (acc.x + selfv.x) * di + bv.x;
  r.y = (acc.y + selfv.y) * di + bv.y;
  r.z = (acc.z + selfv.z) * di + bv.z;
  r.w = (acc.w + selfv.w) * di + bv.w;
  *(float4*)(out + (size_t)w * 128 + colOff) = r;
}

// ---------------- final layer: aggregation + fused log_softmax ----------------
// Wave = 2 nodes x 32 lanes; padded rows, dummy zero row NN in H2.

__global__ __launch_bounds__(256) void k_agg32lsm(const float* __restrict__ H2,
                                                  const float* __restrict__ dis,
                                                  const int* __restrict__ rowstart,
                                                  const int* __restrict__ csr_src,
                                                  const float* __restrict__ bias,
                                                  float* __restrict__ out) {
  int wave = (blockIdx.x * 256 + threadIdx.x) >> 6;
  int lane = threadIdx.x & 63;
  int half = lane >> 5;
  int l = lane & 31;
  int hbase = half * 32;
  int w = wave * 2 + half;
  if (w >= NN) return;   // NN even: both halves exit together
  const float* __restrict__ S = H2 + l;
  float di = dis[w];
  int e0 = rowstart[w], e1 = rowstart[w + 1];
  float acc = 0.f;
  for (int e = e0; e < e1; e += 8) {
    int myIdx = csr_src[e + (l & 7)];
    int s0 = __shfl(myIdx, hbase + 0), s1 = __shfl(myIdx, hbase + 1);
    int s2 = __shfl(myIdx, hbase + 2), s3 = __shfl(myIdx, hbase + 3);
    int s4 = __shfl(myIdx, hbase + 4), s5 = __shfl(myIdx, hbase + 5);
    int s6 = __shfl(myIdx, hbase + 6), s7 = __shfl(myIdx, hbase + 7);
    float h0 = S[(size_t)s0 * 32], h1 = S[(size_t)s1 * 32];
    float h2v = S[(size_t)s2 * 32], h3 = S[(size_t)s3 * 32];
    float h4 = S[(size_t)s4 * 32], h5 = S[(size_t)s5 * 32];
    float h6 = S[(size_t)s6 * 32], h7 = S[(size_t)s7 * 32];
    acc += ((h0 + h1) + (h2v + h3)) + ((h4 + h5) + (h6 + h7));
  }
  float v = (acc + S[(size_t)w * 32]) * di + bias[l];
  float m = v;
  #pragma unroll
  for (int off = 16; off >= 1; off >>= 1) m = fmaxf(m, __shfl_xor(m, off));
  float ex = expf(v - m);
  float s = ex;
  #pragma unroll
  for (int off = 16; off >= 1; off >>= 1) s += __shfl_xor(s, off);
  out[(size_t)w * 32 + l] = v - m - logf(s);
}

// ---------------- BatchNorm stats + fused BN/ReLU/residual ----------------

__global__ __launch_bounds__(256) void k_bnstats(const float* __restrict__ O, float* __restrict__ gsum,
                                                 float* __restrict__ gsumsq) {
  int tid = threadIdx.x;
  int f = tid & 127;
  int half = tid >> 7;
  float s = 0.f, sq = 0.f;
  for (int r = blockIdx.x * 2 + half; r < NN; r += gridDim.x * 2) {
    float v = O[(size_t)r * 128 + f];
    s += v; sq += v * v;
  }
  __shared__ float sm[256], sm2[256];
  sm[tid] = s; sm2[tid] = sq;
  __syncthreads();
  if (tid < 128) {
    atomicAdd(&gsum[f], sm[tid] + sm[tid + 128]);
    atomicAdd(&gsumsq[f], sm2[tid] + sm2[tid + 128]);
  }
}

// computes mu/istd, then RE-ZEROES gstat for the next layer's bnstats
__global__ void k_bnfinal(float* __restrict__ gsum, float* __restrict__ gsumsq,
                          float* __restrict__ mu, float* __restrict__ istd) {
  int f = threadIdx.x;  // 128
  float m = gsum[f] / (float)NN;
  float v = gsumsq[f] / (float)NN - m * m;
  mu[f] = m;
  istd[f] = rsqrtf(v + 1e-5f);
  gsum[f] = 0.f;
  gsumsq[f] = 0.f;
}

__global__ __launch_bounds__(256) void k_fuse(const float* __restrict__ O, const float* Xin, float* Xout,
                                              const float* __restrict__ mu, const float* __restrict__ istd,
                                              const float* __restrict__ g, const float* __restrict__ be) {
  int i = blockIdx.x * 256 + threadIdx.x;
  if (i >= NN * 128 / 4) return;
  int f = (i * 4) & 127;
  float4 ov = ((const float4*)O)[i];
  float4 xv = ((const float4*)Xin)[i];
  float4 r;
  r.x = fmaxf((ov.x - mu[f + 0]) * istd[f + 0] * g[f + 0] + be[f + 0], 0.f) + xv.x;
  r.y = fmaxf((ov.y - mu[f + 1]) * istd[f + 1] * g[f + 1] + be[f + 1], 0.f) + xv.y;
  r.z = fmaxf((ov.z - mu[f + 2]) * istd[f + 2] * g[f + 2] + be[f + 2], 0.f) + xv.z;
  r.w = fmaxf((ov.w - mu[f + 3]) * istd[f + 3] * g[f + 3] + be[f + 3], 0.f) + xv.w;
  ((float4*)Xout)[i] = r;
}

// ---------------- launch ----------------

extern "C" void kernel_launch(void* const* d_in, const int* in_sizes, int n_in,
                              void* d_out, int out_size, void* d_ws, size_t ws_size,
                              hipStream_t stream) {
  const float* x   = (const float*)d_in[0];
  const int*   ei  = (const int*)d_in[1];
  const float* W0  = (const float*)d_in[2];
  const float* b0  = (const float*)d_in[3];
  const float* g0  = (const float*)d_in[4];
  const float* be0 = (const float*)d_in[5];
  const float* W1  = (const float*)d_in[6];
  const float* b1  = (const float*)d_in[7];
  const float* g1  = (const float*)d_in[8];
  const float* be1 = (const float*)d_in[9];
  const float* W2  = (const float*)d_in[10];
  const float* b2  = (const float*)d_in[11];
  float* out = (float*)d_out;
  const int* srcI = ei;
  const int* dstI = ei + NE;

  char* p = (char*)d_ws;
  auto take = [&](size_t bytes) { char* r = p; p += (bytes + 255) & ~(size_t)255; return (void*)r; };
  int*   deg      = (int*)take(NN * 4);
  int*   cursor   = (int*)take(NN * 4);
  int*   rowstart = (int*)take((NN + 1) * 4);
  int*   blksum   = (int*)take(64 * 4);
  int*   blkoff   = (int*)take(64 * 4);
  float* dis      = (float*)take(NN * 4);
  int*   csr      = (int*)take((size_t)NEP * 4);
  float* gstat    = (float*)take(512 * 4);
  float* mu       = (float*)take(128 * 4);
  float* istd     = (float*)take(128 * 4);
  float* hs       = (float*)take((size_t)NNP * 128 * 4);  // fp32, 4-slice-major (stride NNP), pre-scaled
  float* o        = (float*)take((size_t)NN * 128 * 4);
  float* xA       = (float*)take((size_t)NN * 128 * 4);
  float* h2       = (float*)take((size_t)NNP * 32 * 4);

  k_init<<<(NEP + 255) / 256, 256, 0, stream>>>(deg, cursor, gstat, csr);
  k_deg<<<(NE + 255) / 256, 256, 0, stream>>>(dstI, deg);
  k_scan1<<<NBLK, 1024, 0, stream>>>(deg, rowstart, blksum);
  k_scan2<<<1, 64, 0, stream>>>(blksum, blkoff, rowstart);
  k_scan3<<<(NN + 255) / 256, 256, 0, stream>>>(rowstart, blkoff, deg, dis, hs, h2);
  k_fill<<<(NE + 255) / 256, 256, 0, stream>>>(srcI, dstI, rowstart, cursor, csr);

  const int aggGrid = ((NN + 31) / 32) * 4;  // 32 nodes/block x 4 slices

  // ---- layer 0 ----
  k_gemm128<<<(NN + 63) / 64, 256, 0, stream>>>(x, W0, dis, hs, NN);
  k_agg128<<<aggGrid, 256, 0, stream>>>(hs, dis, rowstart, csr, b0, o);
  k_bnstats<<<1024, 256, 0, stream>>>(o, gstat, gstat + 128);
  k_bnfinal<<<1, 128, 0, stream>>>(gstat, gstat + 128, mu, istd);
  k_fuse<<<(NN * 128 / 4 + 255) / 256, 256, 0, stream>>>(o, x, xA, mu, istd, g0, be0);

  // ---- layer 1 ----
  k_gemm128<<<(NN + 63) / 64, 256, 0, stream>>>(xA, W1, dis, hs, NN);
  k_agg128<<<aggGrid, 256, 0, stream>>>(hs, dis, rowstart, csr, b1, o);
  k_bnstats<<<1024, 256, 0, stream>>>(o, gstat, gstat + 128);
  k_bnfinal<<<1, 128, 0, stream>>>(gstat, gstat + 128, mu, istd);
  k_fuse<<<(NN * 128 / 4 + 255) / 256, 256, 0, stream>>>(o, xA, xA, mu, istd, g1, be1);

  // ---- final conv + fused aggregation/log_softmax ----
  k_gemm32<<<(NN + 127) / 128, 256, 0, stream>>>(xA, W2, dis, h2, NN);
  k_agg32lsm<<<(NN + 7) / 8, 256, 0, stream>>>(h2, dis, rowstart, csr, b2, out);
}

// Round 9
// 436.492 us; speedup vs baseline: 1.1811x; 1.0115x over previous
//
#include <hip/hip_runtime.h>
#include <math.h>

#define NN 50000
#define NNP (NN + 1)          // +1 dummy zero row per slice
#define NE 800000
#define NEP 1150000           // NE + 7*NN upper bound on padded edge count
#define NBLK 49               // ceil(NN/1024)

// ---------------- init: zero deg8/gstat, prefill csr with dummy ----------------

__global__ __launch_bounds__(256) void k_init(int* __restrict__ deg8, float* __restrict__ gstat,
                                              int* __restrict__ csr) {
  int i = blockIdx.x * 256 + threadIdx.x;
  if (i < NEP) csr[i] = NN;
  if (i < 8 * NN) deg8[i] = 0;
  if (i < 512) gstat[i] = 0.f;
}

// 8-way sub-bucketed degree count: bucket j = e & 7, plane-major layout
__global__ __launch_bounds__(256) void k_deg(const int* __restrict__ dst, int* __restrict__ deg8) {
  int e = blockIdx.x * 256 + threadIdx.x;
  if (e < NE) atomicAdd(&deg8[(e & 7) * NN + dst[e]], 1);
}

// scan PADDED total degrees; also emit true total degree
__global__ __launch_bounds__(1024) void k_scan1(const int* __restrict__ deg8, int* __restrict__ degtot,
                                                int* __restrict__ excl, int* __restrict__ blksum) {
  __shared__ int sm[1024];
  int t = threadIdx.x;
  int i = blockIdx.x * 1024 + t;
  int tot = 0;
  if (i < NN) {
    #pragma unroll
    for (int j = 0; j < 8; j++) tot += deg8[j * NN + i];
    degtot[i] = tot;
  }
  int v = (i < NN) ? ((tot + 7) & ~7) : 0;
  sm[t] = v;
  __syncthreads();
  for (int off = 1; off < 1024; off <<= 1) {
    int x = (t >= off) ? sm[t - off] : 0;
    __syncthreads();
    sm[t] += x;
    __syncthreads();
  }
  if (i < NN) excl[i] = sm[t] - v;
  if (t == 1023) blksum[blockIdx.x] = sm[t];
}

__global__ void k_scan2(const int* __restrict__ blksum, int* __restrict__ blkoff,
                        int* __restrict__ rowstart) {
  int t = threadIdx.x;  // 64 threads, one wave
  int orig = (t < NBLK) ? blksum[t] : 0;
  int v = orig;
  #pragma unroll
  for (int off = 1; off < 64; off <<= 1) {
    int u = __shfl_up(v, off);
    if (t >= off) v += u;
  }
  if (t < NBLK) blkoff[t] = v - orig;
  if (t == NBLK - 1) rowstart[NN] = v;  // padded edge total
}

// finalize rowstart; dis from TRUE degree; preload cursor8 with ABSOLUTE write
// positions (rowstart + intra-row prefix of sub-bucket counts); zero pad rows.
__global__ __launch_bounds__(256) void k_scan3(int* __restrict__ excl, const int* __restrict__ blkoff,
                                               const int* __restrict__ degtot, const int* __restrict__ deg8,
                                               int* __restrict__ cursor8, float* __restrict__ dis,
                                               float* __restrict__ hs, float* __restrict__ h2) {
  int i = blockIdx.x * 256 + threadIdx.x;
  if (i < NN) {
    int rs = excl[i] + blkoff[i >> 10];
    excl[i] = rs;
    dis[i] = rsqrtf((float)degtot[i] + 1.0f);
    int run = rs;
    #pragma unroll
    for (int j = 0; j < 8; j++) {
      cursor8[j * NN + i] = run;
      run += deg8[j * NN + i];
    }
  }
  if (i < 128) {   // hs pad row: 4 slices x 32 floats
    int slice = i >> 5, c = i & 31;
    hs[(size_t)slice * ((size_t)NNP * 32) + (size_t)NN * 32 + c] = 0.f;
  }
  if (i < 32) h2[(size_t)NN * 32 + i] = 0.f;
}

// scatter: atomic on sub-bucket cursor (avg ~2 same-address collisions), direct write
__global__ __launch_bounds__(256) void k_fill(const int* __restrict__ src, const int* __restrict__ dst,
                                              int* __restrict__ cursor8, int* __restrict__ csr_src) {
  int e = blockIdx.x * 256 + threadIdx.x;
  if (e < NE) {
    int d = dst[e];
    int p = atomicAdd(&cursor8[(e & 7) * NN + d], 1);
    csr_src[p] = src[e];
  }
}

// ---------------- SGEMM 128->128: 64-row tiles, micro 4x8, 4-slice-major out ----------------
// Hs[slice][node][32] fp32 (slice = col>>5, stride NNP rows), pre-scaled by dis[row].

__global__ __launch_bounds__(256) void k_gemm128(const float* __restrict__ X, const float* __restrict__ W,
                                                 const float* __restrict__ dis, float* __restrict__ Hs, int M) {
  __shared__ float As[8][64];
  __shared__ float Bs[8][128];
  const int tid = threadIdx.x;
  const int rg = tid >> 4;   // 0..15: 4-row group
  const int cg = tid & 15;   // 0..15: 8-col group
  const int row0 = blockIdx.x * 64;

  float acc[4][8];
  #pragma unroll
  for (int i = 0; i < 4; i++)
    #pragma unroll
    for (int j = 0; j < 8; j++) acc[i][j] = 0.f;

  const int lr = tid >> 2;        // 0..63
  const int lk = (tid & 3) * 2;   // 0,2,4,6

  for (int kt = 0; kt < 128; kt += 8) {
    float2 av = make_float2(0.f, 0.f);
    int gr = row0 + lr;
    if (gr < M) av = *(const float2*)(X + (size_t)gr * 128 + kt + lk);
    As[lk][lr] = av.x; As[lk + 1][lr] = av.y;
    int k = tid >> 5, c = (tid & 31) * 4;
    *(float4*)&Bs[k][c] = *(const float4*)(W + (size_t)(k + kt) * 128 + c);
    __syncthreads();
    #pragma unroll
    for (int kk = 0; kk < 8; kk++) {
      float a[4], b[8];
      *(float4*)&a[0] = *(const float4*)&As[kk][rg * 4];
      *(float4*)&b[0] = *(const float4*)&Bs[kk][cg * 8];
      *(float4*)&b[4] = *(const float4*)&Bs[kk][cg * 8 + 4];
      #pragma unroll
      for (int i = 0; i < 4; i++)
        #pragma unroll
        for (int j = 0; j < 8; j++) acc[i][j] += a[i] * b[j];
    }
    __syncthreads();
  }

  #pragma unroll
  for (int i = 0; i < 4; i++) {
    int gr = row0 + rg * 4 + i;
    if (gr < M) {
      float d = dis[gr];
      size_t sbase = (size_t)(cg >> 2) * ((size_t)NNP * 32) + (size_t)gr * 32 + (cg & 3) * 8;
      *(float4*)(Hs + sbase)     = make_float4(acc[i][0] * d, acc[i][1] * d, acc[i][2] * d, acc[i][3] * d);
      *(float4*)(Hs + sbase + 4) = make_float4(acc[i][4] * d, acc[i][5] * d, acc[i][6] * d, acc[i][7] * d);
    }
  }
}

// ---------------- SGEMM 128->32: 128-row tiles, micro 8x2, row-major out ----------------

__global__ __launch_bounds__(256) void k_gemm32(const float* __restrict__ X, const float* __restrict__ W,
                                                const float* __restrict__ dis, float* __restrict__ H, int M) {
  __shared__ float As[8][128];
  __shared__ float Bs[8][32];
  const int tid = threadIdx.x;
  const int rg = tid >> 4;
  const int cg = tid & 15;
  const int row0 = blockIdx.x * 128;

  float acc[8][2];
  #pragma unroll
  for (int i = 0; i < 8; i++) { acc[i][0] = 0.f; acc[i][1] = 0.f; }

  const int lr = tid >> 1;
  const int lk = (tid & 1) * 4;

  for (int kt = 0; kt < 128; kt += 8) {
    float4 av = make_float4(0.f, 0.f, 0.f, 0.f);
    int gr = row0 + lr;
    if (gr < M) av = *(const float4*)(X + (size_t)gr * 128 + kt + lk);
    As[lk + 0][lr] = av.x; As[lk + 1][lr] = av.y; As[lk + 2][lr] = av.z; As[lk + 3][lr] = av.w;
    int k = tid >> 5, c = tid & 31;
    Bs[k][c] = W[(size_t)(k + kt) * 32 + c];
    __syncthreads();
    #pragma unroll
    for (int kk = 0; kk < 8; kk++) {
      float a[8];
      *(float4*)&a[0] = *(const float4*)&As[kk][rg * 8];
      *(float4*)&a[4] = *(const float4*)&As[kk][rg * 8 + 4];
      float b0 = Bs[kk][cg * 2], b1 = Bs[kk][cg * 2 + 1];
      #pragma unroll
      for (int i = 0; i < 8; i++) { acc[i][0] += a[i] * b0; acc[i][1] += a[i] * b1; }
    }
    __syncthreads();
  }

  #pragma unroll
  for (int i = 0; i < 8; i++) {
    int gr = row0 + rg * 8 + i;
    if (gr < M) {
      float d = dis[gr];
      *(float2*)(H + (size_t)gr * 32 + cg * 2) = make_float2(acc[i][0] * d, acc[i][1] * d);
    }
  }
}

// ---------------- aggregation, layer 0/1 ----------------
// 4 slices x 32 features = 128 B rows: every gathered cache line is fully used.
// Wave = 8 nodes x 8 feature-lanes (float4 each). Rows padded to x8 with dummy
// node NN (zero row): uniform iterations, no remainder.

__global__ __launch_bounds__(256) void k_agg128(const float* __restrict__ Hs,
                                                const float* __restrict__ dis,
                                                const int* __restrict__ rowstart,
                                                const int* __restrict__ csr_src,
                                                const float* __restrict__ bias,
                                                float* __restrict__ out) {
  int slice = blockIdx.x & 3;
  int lane = threadIdx.x & 63;
  int node_sub = lane >> 3;      // 0..7
  int fl = lane & 7;             // 0..7 (float4 each)
  int base = node_sub * 8;
  int w = (blockIdx.x >> 2) * 32 + (threadIdx.x >> 6) * 8 + node_sub;
  if (w >= NN) return;
  const float* __restrict__ S = Hs + (size_t)slice * ((size_t)NNP * 32) + fl * 4;
  float di = dis[w];
  int e0 = rowstart[w], e1 = rowstart[w + 1];   // padded, group-uniform
  float4 acc = make_float4(0.f, 0.f, 0.f, 0.f);
  for (int e = e0; e < e1; e += 8) {
    int myIdx = csr_src[e + fl];               // one instr: 64 indices (8/node)
    int s0 = __shfl(myIdx, base + 0), s1 = __shfl(myIdx, base + 1);
    int s2 = __shfl(myIdx, base + 2), s3 = __shfl(myIdx, base + 3);
    int s4 = __shfl(myIdx, base + 4), s5 = __shfl(myIdx, base + 5);
    int s6 = __shfl(myIdx, base + 6), s7 = __shfl(myIdx, base + 7);
    float4 g0 = *(const float4*)(S + (size_t)s0 * 32);
    float4 g1 = *(const float4*)(S + (size_t)s1 * 32);
    float4 g2 = *(const float4*)(S + (size_t)s2 * 32);
    float4 g3 = *(const float4*)(S + (size_t)s3 * 32);
    float4 g4 = *(const float4*)(S + (size_t)s4 * 32);
    float4 g5 = *(const float4*)(S + (size_t)s5 * 32);
    float4 g6 = *(const float4*)(S + (size_t)s6 * 32);
    float4 g7 = *(const float4*)(S + (size_t)s7 * 32);
    acc.x += ((g0.x + g1.x) + (g2.x + g3.x)) + ((g4.x + g5.x) + (g6.x + g7.x));
    acc.y += ((g0.y + g1.y) + (g2.y + g3.y)) + ((g4.y + g5.y) + (g6.y + g7.y));
    acc.z += ((g0.z + g1.z) + (g2.z + g3.z)) + ((g4.z + g5.z) + (g6.z + g7.z));
    acc.w += ((g0.w + g1.w) + (g2.w + g3.w)) + ((g4.w + g5.w) + (g6.w + g7.w));
  }
  float4 selfv = *(const float4*)(S + (size_t)w * 32);
  int colOff = slice * 32 + fl * 4;
  float4 bv = *(const float4*)(bias + colOff);
  float4 r;
  r.x = (acc.x + selfv.x) * di + bv.x;
  r.y = (acc.y + selfv.y) * di + bv.y;
  r.z = (acc.z + selfv.z) * di + bv.z;
  r.w = (acc.w + selfv.w) * di + bv.w;
  *(float4*)(out + (size_t)w * 128 + colOff) = r;
}

// ---------------- final layer: aggregation + fused log_softmax ----------------
// Wave = 2 nodes x 32 lanes; padded rows, dummy zero row NN in H2.

__global__ __launch_bounds__(256) void k_agg32lsm(const float* __restrict__ H2,
                                                  const float* __restrict__ dis,
                                                  const int* __restrict__ rowstart,
                                                  const int* __restrict__ csr_src,
                                                  const float* __restrict__ bias,
                                                  float* __restrict__ out) {
  int wave = (blockIdx.x * 256 + threadIdx.x) >> 6;
  int lane = threadIdx.x & 63;
  int half = lane >> 5;
  int l = lane & 31;
  int hbase = half * 32;
  int w = wave * 2 + half;
  if (w >= NN) return;   // NN even: both halves exit together
  const float* __restrict__ S = H2 + l;
  float di = dis[w];
  int e0 = rowstart[w], e1 = rowstart[w + 1];
  float acc = 0.f;
  for (int e = e0; e < e1; e += 8) {
    int myIdx = csr_src[e + (l & 7)];
    int s0 = __shfl(myIdx, hbase + 0), s1 = __shfl(myIdx, hbase + 1);
    int s2 = __shfl(myIdx, hbase + 2), s3 = __shfl(myIdx, hbase + 3);
    int s4 = __shfl(myIdx, hbase + 4), s5 = __shfl(myIdx, hbase + 5);
    int s6 = __shfl(myIdx, hbase + 6), s7 = __shfl(myIdx, hbase + 7);
    float h0 = S[(size_t)s0 * 32], h1 = S[(size_t)s1 * 32];
    float h2v = S[(size_t)s2 * 32], h3 = S[(size_t)s3 * 32];
    float h4 = S[(size_t)s4 * 32], h5 = S[(size_t)s5 * 32];
    float h6 = S[(size_t)s6 * 32], h7 = S[(size_t)s7 * 32];
    acc += ((h0 + h1) + (h2v + h3)) + ((h4 + h5) + (h6 + h7));
  }
  float v = (acc + S[(size_t)w * 32]) * di + bias[l];
  float m = v;
  #pragma unroll
  for (int off = 16; off >= 1; off >>= 1) m = fmaxf(m, __shfl_xor(m, off));
  float ex = expf(v - m);
  float s = ex;
  #pragma unroll
  for (int off = 16; off >= 1; off >>= 1) s += __shfl_xor(s, off);
  out[(size_t)w * 32 + l] = v - m - logf(s);
}

// ---------------- BatchNorm stats + fused BN/ReLU/residual ----------------

__global__ __launch_bounds__(256) void k_bnstats(const float* __restrict__ O, float* __restrict__ gsum,
                                                 float* __restrict__ gsumsq) {
  int tid = threadIdx.x;
  int f = tid & 127;
  int half = tid >> 7;
  float s = 0.f, sq = 0.f;
  for (int r = blockIdx.x * 2 + half; r < NN; r += gridDim.x * 2) {
    float v = O[(size_t)r * 128 + f];
    s += v; sq += v * v;
  }
  __shared__ float sm[256], sm2[256];
  sm[tid] = s; sm2[tid] = sq;
  __syncthreads();
  if (tid < 128) {
    atomicAdd(&gsum[f], sm[tid] + sm[tid + 128]);
    atomicAdd(&gsumsq[f], sm2[tid] + sm2[tid + 128]);
  }
}

// computes mu/istd, then RE-ZEROES gstat for the next layer's bnstats
__global__ void k_bnfinal(float* __restrict__ gsum, float* __restrict__ gsumsq,
                          float* __restrict__ mu, float* __restrict__ istd) {
  int f = threadIdx.x;  // 128
  float m = gsum[f] / (float)NN;
  float v = gsumsq[f] / (float)NN - m * m;
  mu[f] = m;
  istd[f] = rsqrtf(v + 1e-5f);
  gsum[f] = 0.f;
  gsumsq[f] = 0.f;
}

__global__ __launch_bounds__(256) void k_fuse(const float* __restrict__ O, const float* Xin, float* Xout,
                                              const float* __restrict__ mu, const float* __restrict__ istd,
                                              const float* __restrict__ g, const float* __restrict__ be) {
  int i = blockIdx.x * 256 + threadIdx.x;
  if (i >= NN * 128 / 4) return;
  int f = (i * 4) & 127;
  float4 ov = ((const float4*)O)[i];
  float4 xv = ((const float4*)Xin)[i];
  float4 r;
  r.x = fmaxf((ov.x - mu[f + 0]) * istd[f + 0] * g[f + 0] + be[f + 0], 0.f) + xv.x;
  r.y = fmaxf((ov.y - mu[f + 1]) * istd[f + 1] * g[f + 1] + be[f + 1], 0.f) + xv.y;
  r.z = fmaxf((ov.z - mu[f + 2]) * istd[f + 2] * g[f + 2] + be[f + 2], 0.f) + xv.z;
  r.w = fmaxf((ov.w - mu[f + 3]) * istd[f + 3] * g[f + 3] + be[f + 3], 0.f) + xv.w;
  ((float4*)Xout)[i] = r;
}

// ---------------- launch ----------------

extern "C" void kernel_launch(void* const* d_in, const int* in_sizes, int n_in,
                              void* d_out, int out_size, void* d_ws, size_t ws_size,
                              hipStream_t stream) {
  const float* x   = (const float*)d_in[0];
  const int*   ei  = (const int*)d_in[1];
  const float* W0  = (const float*)d_in[2];
  const float* b0  = (const float*)d_in[3];
  const float* g0  = (const float*)d_in[4];
  const float* be0 = (const float*)d_in[5];
  const float* W1  = (const float*)d_in[6];
  const float* b1  = (const float*)d_in[7];
  const float* g1  = (const float*)d_in[8];
  const float* be1 = (const float*)d_in[9];
  const float* W2  = (const float*)d_in[10];
  const float* b2  = (const float*)d_in[11];
  float* out = (float*)d_out;
  const int* srcI = ei;
  const int* dstI = ei + NE;

  char* p = (char*)d_ws;
  auto take = [&](size_t bytes) { char* r = p; p += (bytes + 255) & ~(size_t)255; return (void*)r; };
  int*   deg8     = (int*)take((size_t)8 * NN * 4);
  int*   cursor8  = (int*)take((size_t)8 * NN * 4);
  int*   degtot   = (int*)take(NN * 4);
  int*   rowstart = (int*)take((NN + 1) * 4);
  int*   blksum   = (int*)take(64 * 4);
  int*   blkoff   = (int*)take(64 * 4);
  float* dis      = (float*)take(NN * 4);
  int*   csr      = (int*)take((size_t)NEP * 4);
  float* gstat    = (float*)take(512 * 4);
  float* mu       = (float*)take(128 * 4);
  float* istd     = (float*)take(128 * 4);
  float* hs       = (float*)take((size_t)NNP * 128 * 4);  // fp32, 4-slice-major (stride NNP), pre-scaled
  float* o        = (float*)take((size_t)NN * 128 * 4);
  float* xA       = (float*)take((size_t)NN * 128 * 4);
  float* h2       = (float*)take((size_t)NNP * 32 * 4);

  k_init<<<(NEP + 255) / 256, 256, 0, stream>>>(deg8, gstat, csr);
  k_deg<<<(NE + 255) / 256, 256, 0, stream>>>(dstI, deg8);
  k_scan1<<<NBLK, 1024, 0, stream>>>(deg8, degtot, rowstart, blksum);
  k_scan2<<<1, 64, 0, stream>>>(blksum, blkoff, rowstart);
  k_scan3<<<(NN + 255) / 256, 256, 0, stream>>>(rowstart, blkoff, degtot, deg8, cursor8, dis, hs, h2);
  k_fill<<<(NE + 255) / 256, 256, 0, stream>>>(srcI, dstI, cursor8, csr);

  const int aggGrid = ((NN + 31) / 32) * 4;  // 32 nodes/block x 4 slices

  // ---- layer 0 ----
  k_gemm128<<<(NN + 63) / 64, 256, 0, stream>>>(x, W0, dis, hs, NN);
  k_agg128<<<aggGrid, 256, 0, stream>>>(hs, dis, rowstart, csr, b0, o);
  k_bnstats<<<1024, 256, 0, stream>>>(o, gstat, gstat + 128);
  k_bnfinal<<<1, 128, 0, stream>>>(gstat, gstat + 128, mu, istd);
  k_fuse<<<(NN * 128 / 4 + 255) / 256, 256, 0, stream>>>(o, x, xA, mu, istd, g0, be0);

  // ---- layer 1 ----
  k_gemm128<<<(NN + 63) / 64, 256, 0, stream>>>(xA, W1, dis, hs, NN);
  k_agg128<<<aggGrid, 256, 0, stream>>>(hs, dis, rowstart, csr, b1, o);
  k_bnstats<<<1024, 256, 0, stream>>>(o, gstat, gstat + 128);
  k_bnfinal<<<1, 128, 0, stream>>>(gstat, gstat + 128, mu, istd);
  k_fuse<<<(NN * 128 / 4 + 255) / 256, 256, 0, stream>>>(o, xA, xA, mu, istd, g1, be1);

  // ---- final conv + fused aggregation/log_softmax ----
  k_gemm32<<<(NN + 127) / 128, 256, 0, stream>>>(xA, W2, dis, h2, NN);
  k_agg32lsm<<<(NN + 7) / 8, 256, 0, stream>>>(h2, dis, rowstart, csr, b2, out);
}

// Round 10
// 434.699 us; speedup vs baseline: 1.1860x; 1.0041x over previous
//
#include <hip/hip_runtime.h>
#include <math.h>

#define NN 50000
#define NNP (NN + 1)          // +1 dummy zero row per slice
#define NE 800000
#define NEP 1150000           // NE + 7*NN upper bound on padded edge count
#define NBLK 49               // ceil(NN/1024)
#define NBKT 7                // dst-range buckets (d >> 13)
#define BCAP 262144           // per-bucket bin capacity (expected ~131k, 2x margin)

// ---------------- init: zero deg8/gstat/binCnt, prefill csr with dummy ----------------

__global__ __launch_bounds__(256) void k_init(int* __restrict__ deg8, float* __restrict__ gstat,
                                              int* __restrict__ csr, int* __restrict__ binCnt) {
  int i = blockIdx.x * 256 + threadIdx.x;
  if (i < NEP) csr[i] = NN;
  if (i < 8 * NN) deg8[i] = 0;
  if (i < 512) gstat[i] = 0.f;
  if (i < NBKT) binCnt[i] = 0;
}

// ---------------- pass A: degree count + dst-range binning ----------------
// 1024-thread blocks; LDS histogram gives intra-block rank; one global atomic
// per (block,bucket) reserves space; block-contiguous int2 writes (full lines).

__global__ __launch_bounds__(1024) void k_binA(const int* __restrict__ src, const int* __restrict__ dst,
                                               int* __restrict__ deg8, int* __restrict__ binCnt,
                                               int2* __restrict__ bin) {
  __shared__ int lcnt[NBKT], lbase[NBKT];
  int tid = threadIdx.x;
  if (tid < NBKT) lcnt[tid] = 0;
  __syncthreads();
  int e = blockIdx.x * 1024 + tid;
  bool act = e < NE;
  int d = 0, s = 0, b = 0, rank = 0;
  if (act) {
    d = dst[e]; s = src[e];
    b = d >> 13;                       // 0..6
    atomicAdd(&deg8[(e & 7) * NN + d], 1);
    rank = atomicAdd(&lcnt[b], 1);
  }
  __syncthreads();
  if (tid < NBKT && lcnt[tid] > 0) lbase[tid] = atomicAdd(&binCnt[tid], lcnt[tid]);
  __syncthreads();
  if (act) bin[(size_t)b * BCAP + lbase[b] + rank] = make_int2(d, s);
}

// scan PADDED total degrees; also emit true total degree
__global__ __launch_bounds__(1024) void k_scan1(const int* __restrict__ deg8, int* __restrict__ degtot,
                                                int* __restrict__ excl, int* __restrict__ blksum) {
  __shared__ int sm[1024];
  int t = threadIdx.x;
  int i = blockIdx.x * 1024 + t;
  int tot = 0;
  if (i < NN) {
    #pragma unroll
    for (int j = 0; j < 8; j++) tot += deg8[j * NN + i];
    degtot[i] = tot;
  }
  int v = (i < NN) ? ((tot + 7) & ~7) : 0;
  sm[t] = v;
  __syncthreads();
  for (int off = 1; off < 1024; off <<= 1) {
    int x = (t >= off) ? sm[t - off] : 0;
    __syncthreads();
    sm[t] += x;
    __syncthreads();
  }
  if (i < NN) excl[i] = sm[t] - v;
  if (t == 1023) blksum[blockIdx.x] = sm[t];
}

__global__ void k_scan2(const int* __restrict__ blksum, int* __restrict__ blkoff,
                        int* __restrict__ rowstart) {
  int t = threadIdx.x;  // 64 threads, one wave
  int orig = (t < NBLK) ? blksum[t] : 0;
  int v = orig;
  #pragma unroll
  for (int off = 1; off < 64; off <<= 1) {
    int u = __shfl_up(v, off);
    if (t >= off) v += u;
  }
  if (t < NBLK) blkoff[t] = v - orig;
  if (t == NBLK - 1) rowstart[NN] = v;  // padded edge total
}

// finalize rowstart; dis from TRUE degree; preload cursor with row start; zero pads
__global__ __launch_bounds__(256) void k_scan3(int* __restrict__ excl, const int* __restrict__ blkoff,
                                               const int* __restrict__ degtot, int* __restrict__ cursor,
                                               float* __restrict__ dis,
                                               float* __restrict__ hs, float* __restrict__ h2) {
  int i = blockIdx.x * 256 + threadIdx.x;
  if (i < NN) {
    int rs = excl[i] + blkoff[i >> 10];
    excl[i] = rs;
    cursor[i] = rs;
    dis[i] = rsqrtf((float)degtot[i] + 1.0f);
  }
  if (i < 128) {   // hs pad row: 4 slices x 32 floats
    int slice = i >> 5, c = i & 31;
    hs[(size_t)slice * ((size_t)NNP * 32) + (size_t)NN * 32 + c] = 0.f;
  }
  if (i < 32) h2[(size_t)NN * 32 + i] = 0.f;
}

// ---------------- pass B: scatter within XCD-pinned bucket ----------------
// bucket = blockIdx & 7 (blocks of one bucket land on one XCD if %8 round-robin
// holds): all writes to that bucket's contiguous csr region stay in one L2.

__global__ __launch_bounds__(256) void k_fillB(const int2* __restrict__ bin, const int* __restrict__ binCnt,
                                               int* __restrict__ cursor, int* __restrict__ csr_src) {
  int b = blockIdx.x & 7;
  if (b >= NBKT) return;
  int q = blockIdx.x >> 3;             // 0..63
  int cnt = binCnt[b];
  const int2* __restrict__ B = bin + (size_t)b * BCAP;
  for (int i = q * 256 + threadIdx.x; i < cnt; i += 64 * 256) {
    int2 ds = B[i];
    int p = atomicAdd(&cursor[ds.x], 1);
    csr_src[p] = ds.y;
  }
}

// ---------------- SGEMM 128->128: 64-row tiles, micro 4x8, 4-slice-major out ----------------
// Hs[slice][node][32] fp32 (slice = col>>5, stride NNP rows), pre-scaled by dis[row].

__global__ __launch_bounds__(256) void k_gemm128(const float* __restrict__ X, const float* __restrict__ W,
                                                 const float* __restrict__ dis, float* __restrict__ Hs, int M) {
  __shared__ float As[8][64];
  __shared__ float Bs[8][128];
  const int tid = threadIdx.x;
  const int rg = tid >> 4;   // 0..15: 4-row group
  const int cg = tid & 15;   // 0..15: 8-col group
  const int row0 = blockIdx.x * 64;

  float acc[4][8];
  #pragma unroll
  for (int i = 0; i < 4; i++)
    #pragma unroll
    for (int j = 0; j < 8; j++) acc[i][j] = 0.f;

  const int lr = tid >> 2;        // 0..63
  const int lk = (tid & 3) * 2;   // 0,2,4,6

  for (int kt = 0; kt < 128; kt += 8) {
    float2 av = make_float2(0.f, 0.f);
    int gr = row0 + lr;
    if (gr < M) av = *(const float2*)(X + (size_t)gr * 128 + kt + lk);
    As[lk][lr] = av.x; As[lk + 1][lr] = av.y;
    int k = tid >> 5, c = (tid & 31) * 4;
    *(float4*)&Bs[k][c] = *(const float4*)(W + (size_t)(k + kt) * 128 + c);
    __syncthreads();
    #pragma unroll
    for (int kk = 0; kk < 8; kk++) {
      float a[4], b[8];
      *(float4*)&a[0] = *(const float4*)&As[kk][rg * 4];
      *(float4*)&b[0] = *(const float4*)&Bs[kk][cg * 8];
      *(float4*)&b[4] = *(const float4*)&Bs[kk][cg * 8 + 4];
      #pragma unroll
      for (int i = 0; i < 4; i++)
        #pragma unroll
        for (int j = 0; j < 8; j++) acc[i][j] += a[i] * b[j];
    }
    __syncthreads();
  }

  #pragma unroll
  for (int i = 0; i < 4; i++) {
    int gr = row0 + rg * 4 + i;
    if (gr < M) {
      float d = dis[gr];
      size_t sbase = (size_t)(cg >> 2) * ((size_t)NNP * 32) + (size_t)gr * 32 + (cg & 3) * 8;
      *(float4*)(Hs + sbase)     = make_float4(acc[i][0] * d, acc[i][1] * d, acc[i][2] * d, acc[i][3] * d);
      *(float4*)(Hs + sbase + 4) = make_float4(acc[i][4] * d, acc[i][5] * d, acc[i][6] * d, acc[i][7] * d);
    }
  }
}

// ---------------- SGEMM 128->32: 128-row tiles, micro 8x2, row-major out ----------------

__global__ __launch_bounds__(256) void k_gemm32(const float* __restrict__ X, const float* __restrict__ W,
                                                const float* __restrict__ dis, float* __restrict__ H, int M) {
  __shared__ float As[8][128];
  __shared__ float Bs[8][32];
  const int tid = threadIdx.x;
  const int rg = tid >> 4;
  const int cg = tid & 15;
  const int row0 = blockIdx.x * 128;

  float acc[8][2];
  #pragma unroll
  for (int i = 0; i < 8; i++) { acc[i][0] = 0.f; acc[i][1] = 0.f; }

  const int lr = tid >> 1;
  const int lk = (tid & 1) * 4;

  for (int kt = 0; kt < 128; kt += 8) {
    float4 av = make_float4(0.f, 0.f, 0.f, 0.f);
    int gr = row0 + lr;
    if (gr < M) av = *(const float4*)(X + (size_t)gr * 128 + kt + lk);
    As[lk + 0][lr] = av.x; As[lk + 1][lr] = av.y; As[lk + 2][lr] = av.z; As[lk + 3][lr] = av.w;
    int k = tid >> 5, c = tid & 31;
    Bs[k][c] = W[(size_t)(k + kt) * 32 + c];
    __syncthreads();
    #pragma unroll
    for (int kk = 0; kk < 8; kk++) {
      float a[8];
      *(float4*)&a[0] = *(const float4*)&As[kk][rg * 8];
      *(float4*)&a[4] = *(const float4*)&As[kk][rg * 8 + 4];
      float b0 = Bs[kk][cg * 2], b1 = Bs[kk][cg * 2 + 1];
      #pragma unroll
      for (int i = 0; i < 8; i++) { acc[i][0] += a[i] * b0; acc[i][1] += a[i] * b1; }
    }
    __syncthreads();
  }

  #pragma unroll
  for (int i = 0; i < 8; i++) {
    int gr = row0 + rg * 8 + i;
    if (gr < M) {
      float d = dis[gr];
      *(float2*)(H + (size_t)gr * 32 + cg * 2) = make_float2(acc[i][0] * d, acc[i][1] * d);
    }
  }
}

// ---------------- aggregation, layer 0/1 ----------------
// 4 slices x 32 features = 128 B rows: every gathered cache line is fully used.
// Wave = 8 nodes x 8 feature-lanes (float4 each). Rows padded to x8 with dummy
// node NN (zero row): uniform iterations, no remainder.

__global__ __launch_bounds__(256) void k_agg128(const float* __restrict__ Hs,
                                                const float* __restrict__ dis,
                                                const int* __restrict__ rowstart,
                                                const int* __restrict__ csr_src,
                                                const float* __restrict__ bias,
                                                float* __restrict__ out) {
  int slice = blockIdx.x & 3;
  int lane = threadIdx.x & 63;
  int node_sub = lane >> 3;      // 0..7
  int fl = lane & 7;             // 0..7 (float4 each)
  int base = node_sub * 8;
  int w = (blockIdx.x >> 2) * 32 + (threadIdx.x >> 6) * 8 + node_sub;
  if (w >= NN) return;
  const float* __restrict__ S = Hs + (size_t)slice * ((size_t)NNP * 32) + fl * 4;
  float di = dis[w];
  int e0 = rowstart[w], e1 = rowstart[w + 1];   // padded, group-uniform
  float4 acc = make_float4(0.f, 0.f, 0.f, 0.f);
  for (int e = e0; e < e1; e += 8) {
    int myIdx = csr_src[e + fl];               // one instr: 64 indices (8/node)
    int s0 = __shfl(myIdx, base + 0), s1 = __shfl(myIdx, base + 1);
    int s2 = __shfl(myIdx, base + 2), s3 = __shfl(myIdx, base + 3);
    int s4 = __shfl(myIdx, base + 4), s5 = __shfl(myIdx, base + 5);
    int s6 = __shfl(myIdx, base + 6), s7 = __shfl(myIdx, base + 7);
    float4 g0 = *(const float4*)(S + (size_t)s0 * 32);
    float4 g1 = *(const float4*)(S + (size_t)s1 * 32);
    float4 g2 = *(const float4*)(S + (size_t)s2 * 32);
    float4 g3 = *(const float4*)(S + (size_t)s3 * 32);
    float4 g4 = *(const float4*)(S + (size_t)s4 * 32);
    float4 g5 = *(const float4*)(S + (size_t)s5 * 32);
    float4 g6 = *(const float4*)(S + (size_t)s6 * 32);
    float4 g7 = *(const float4*)(S + (size_t)s7 * 32);
    acc.x += ((g0.x + g1.x) + (g2.x + g3.x)) + ((g4.x + g5.x) + (g6.x + g7.x));
    acc.y += ((g0.y + g1.y) + (g2.y + g3.y)) + ((g4.y + g5.y) + (g6.y + g7.y));
    acc.z += ((g0.z + g1.z) + (g2.z + g3.z)) + ((g4.z + g5.z) + (g6.z + g7.z));
    acc.w += ((g0.w + g1.w) + (g2.w + g3.w)) + ((g4.w + g5.w) + (g6.w + g7.w));
  }
  float4 selfv = *(const float4*)(S + (size_t)w * 32);
  int colOff = slice * 32 + fl * 4;
  float4 bv = *(const float4*)(bias + colOff);
  float4 r;
  r.x = (acc.x + selfv.x) * di + bv.x;
  r.y = (acc.y + selfv.y) * di + bv.y;
  r.z = (acc.z + selfv.z) * di + bv.z;
  r.w = (acc.w + selfv.w) * di + bv.w;
  *(float4*)(out + (size_t)w * 128 + colOff) = r;
}

// ---------------- final layer: aggregation + fused log_softmax ----------------
// Wave = 2 nodes x 32 lanes; padded rows, dummy zero row NN in H2.

__global__ __launch_bounds__(256) void k_agg32lsm(const float* __restrict__ H2,
                                                  const float* __restrict__ dis,
                                                  const int* __restrict__ rowstart,
                                                  const int* __restrict__ csr_src,
                                                  const float* __restrict__ bias,
                                                  float* __restrict__ out) {
  int wave = (blockIdx.x * 256 + threadIdx.x) >> 6;
  int lane = threadIdx.x & 63;
  int half = lane >> 5;
  int l = lane & 31;
  int hbase = half * 32;
  int w = wave * 2 + half;
  if (w >= NN) return;   // NN even: both halves exit together
  const float* __restrict__ S = H2 + l;
  float di = dis[w];
  int e0 = rowstart[w], e1 = rowstart[w + 1];
  float acc = 0.f;
  for (int e = e0; e < e1; e += 8) {
    int myIdx = csr_src[e + (l & 7)];
    int s0 = __shfl(myIdx, hbase + 0), s1 = __shfl(myIdx, hbase + 1);
    int s2 = __shfl(myIdx, hbase + 2), s3 = __shfl(myIdx, hbase + 3);
    int s4 = __shfl(myIdx, hbase + 4), s5 = __shfl(myIdx, hbase + 5);
    int s6 = __shfl(myIdx, hbase + 6), s7 = __shfl(myIdx, hbase + 7);
    float h0 = S[(size_t)s0 * 32], h1 = S[(size_t)s1 * 32];
    float h2v = S[(size_t)s2 * 32], h3 = S[(size_t)s3 * 32];
    float h4 = S[(size_t)s4 * 32], h5 = S[(size_t)s5 * 32];
    float h6 = S[(size_t)s6 * 32], h7 = S[(size_t)s7 * 32];
    acc += ((h0 + h1) + (h2v + h3)) + ((h4 + h5) + (h6 + h7));
  }
  float v = (acc + S[(size_t)w * 32]) * di + bias[l];
  float m = v;
  #pragma unroll
  for (int off = 16; off >= 1; off >>= 1) m = fmaxf(m, __shfl_xor(m, off));
  float ex = expf(v - m);
  float s = ex;
  #pragma unroll
  for (int off = 16; off >= 1; off >>= 1) s += __shfl_xor(s, off);
  out[(size_t)w * 32 + l] = v - m - logf(s);
}

// ---------------- BatchNorm stats + fused BN/ReLU/residual ----------------

__global__ __launch_bounds__(256) void k_bnstats(const float* __restrict__ O, float* __restrict__ gsum,
                                                 float* __restrict__ gsumsq) {
  int tid = threadIdx.x;
  int f = tid & 127;
  int half = tid >> 7;
  float s = 0.f, sq = 0.f;
  for (int r = blockIdx.x * 2 + half; r < NN; r += gridDim.x * 2) {
    float v = O[(size_t)r * 128 + f];
    s += v; sq += v * v;
  }
  __shared__ float sm[256], sm2[256];
  sm[tid] = s; sm2[tid] = sq;
  __syncthreads();
  if (tid < 128) {
    atomicAdd(&gsum[f], sm[tid] + sm[tid + 128]);
    atomicAdd(&gsumsq[f], sm2[tid] + sm2[tid + 128]);
  }
}

// computes mu/istd, then RE-ZEROES gstat for the next layer's bnstats
__global__ void k_bnfinal(float* __restrict__ gsum, float* __restrict__ gsumsq,
                          float* __restrict__ mu, float* __restrict__ istd) {
  int f = threadIdx.x;  // 128
  float m = gsum[f] / (float)NN;
  float v = gsumsq[f] / (float)NN - m * m;
  mu[f] = m;
  istd[f] = rsqrtf(v + 1e-5f);
  gsum[f] = 0.f;
  gsumsq[f] = 0.f;
}

__global__ __launch_bounds__(256) void k_fuse(const float* __restrict__ O, const float* Xin, float* Xout,
                                              const float* __restrict__ mu, const float* __restrict__ istd,
                                              const float* __restrict__ g, const float* __restrict__ be) {
  int i = blockIdx.x * 256 + threadIdx.x;
  if (i >= NN * 128 / 4) return;
  int f = (i * 4) & 127;
  float4 ov = ((const float4*)O)[i];
  float4 xv = ((const float4*)Xin)[i];
  float4 r;
  r.x = fmaxf((ov.x - mu[f + 0]) * istd[f + 0] * g[f + 0] + be[f + 0], 0.f) + xv.x;
  r.y = fmaxf((ov.y - mu[f + 1]) * istd[f + 1] * g[f + 1] + be[f + 1], 0.f) + xv.y;
  r.z = fmaxf((ov.z - mu[f + 2]) * istd[f + 2] * g[f + 2] + be[f + 2], 0.f) + xv.z;
  r.w = fmaxf((ov.w - mu[f + 3]) * istd[f + 3] * g[f + 3] + be[f + 3], 0.f) + xv.w;
  ((float4*)Xout)[i] = r;
}

// ---------------- launch ----------------

extern "C" void kernel_launch(void* const* d_in, const int* in_sizes, int n_in,
                              void* d_out, int out_size, void* d_ws, size_t ws_size,
                              hipStream_t stream) {
  const float* x   = (const float*)d_in[0];
  const int*   ei  = (const int*)d_in[1];
  const float* W0  = (const float*)d_in[2];
  const float* b0  = (const float*)d_in[3];
  const float* g0  = (const float*)d_in[4];
  const float* be0 = (const float*)d_in[5];
  const float* W1  = (const float*)d_in[6];
  const float* b1  = (const float*)d_in[7];
  const float* g1  = (const float*)d_in[8];
  const float* be1 = (const float*)d_in[9];
  const float* W2  = (const float*)d_in[10];
  const float* b2  = (const float*)d_in[11];
  float* out = (float*)d_out;
  const int* srcI = ei;
  const int* dstI = ei + NE;

  char* p = (char*)d_ws;
  auto take = [&](size_t bytes) { char* r = p; p += (bytes + 255) & ~(size_t)255; return (void*)r; };
  int*   deg8     = (int*)take((size_t)8 * NN * 4);
  int*   cursor   = (int*)take(NN * 4);
  int*   degtot   = (int*)take(NN * 4);
  int*   rowstart = (int*)take((NN + 1) * 4);
  int*   blksum   = (int*)take(64 * 4);
  int*   blkoff   = (int*)take(64 * 4);
  int*   binCnt   = (int*)take(8 * 4);
  float* dis      = (float*)take(NN * 4);
  int*   csr      = (int*)take((size_t)NEP * 4);
  int2*  bin      = (int2*)take((size_t)NBKT * BCAP * 8);
  float* gstat    = (float*)take(512 * 4);
  float* mu       = (float*)take(128 * 4);
  float* istd     = (float*)take(128 * 4);
  float* hs       = (float*)take((size_t)NNP * 128 * 4);  // fp32, 4-slice-major (stride NNP), pre-scaled
  float* o        = (float*)take((size_t)NN * 128 * 4);
  float* xA       = (float*)take((size_t)NN * 128 * 4);
  float* h2       = (float*)take((size_t)NNP * 32 * 4);

  k_init<<<(NEP + 255) / 256, 256, 0, stream>>>(deg8, gstat, csr, binCnt);
  k_binA<<<(NE + 1023) / 1024, 1024, 0, stream>>>(srcI, dstI, deg8, binCnt, bin);
  k_scan1<<<NBLK, 1024, 0, stream>>>(deg8, degtot, rowstart, blksum);
  k_scan2<<<1, 64, 0, stream>>>(blksum, blkoff, rowstart);
  k_scan3<<<(NN + 255) / 256, 256, 0, stream>>>(rowstart, blkoff, degtot, cursor, dis, hs, h2);
  k_fillB<<<512, 256, 0, stream>>>(bin, binCnt, cursor, csr);

  const int aggGrid = ((NN + 31) / 32) * 4;  // 32 nodes/block x 4 slices

  // ---- layer 0 ----
  k_gemm128<<<(NN + 63) / 64, 256, 0, stream>>>(x, W0, dis, hs, NN);
  k_agg128<<<aggGrid, 256, 0, stream>>>(hs, dis, rowstart, csr, b0, o);
  k_bnstats<<<1024, 256, 0, stream>>>(o, gstat, gstat + 128);
  k_bnfinal<<<1, 128, 0, stream>>>(gstat, gstat + 128, mu, istd);
  k_fuse<<<(NN * 128 / 4 + 255) / 256, 256, 0, stream>>>(o, x, xA, mu, istd, g0, be0);

  // ---- layer 1 ----
  k_gemm128<<<(NN + 63) / 64, 256, 0, stream>>>(xA, W1, dis, hs, NN);
  k_agg128<<<aggGrid, 256, 0, stream>>>(hs, dis, rowstart, csr, b1, o);
  k_bnstats<<<1024, 256, 0, stream>>>(o, gstat, gstat + 128);
  k_bnfinal<<<1, 128, 0, stream>>>(gstat, gstat + 128, mu, istd);
  k_fuse<<<(NN * 128 / 4 + 255) / 256, 256, 0, stream>>>(o, xA, xA, mu, istd, g1, be1);

  // ---- final conv + fused aggregation/log_softmax ----
  k_gemm32<<<(NN + 127) / 128, 256, 0, stream>>>(xA, W2, dis, h2, NN);
  k_agg32lsm<<<(NN + 7) / 8, 256, 0, stream>>>(h2, dis, rowstart, csr, b2, out);
}

// Round 11
// 412.336 us; speedup vs baseline: 1.2503x; 1.0542x over previous
//
#include <hip/hip_runtime.h>
#include <math.h>

#define NN 50000
#define NNP (NN + 1)          // +1 dummy zero row per slice
#define NE 800000
#define NEP 1150000           // NE + 7*NN upper bound on padded edge count
#define NBLK 49               // ceil(NN/1024)
#define NBKT 7                // dst-range buckets (d >> 13)
#define BCAP 262144           // per-bucket bin capacity

// bf16 helpers (RNE pack, shift unpack)
__device__ inline unsigned int f2bf(float f) {
  unsigned int u = __float_as_uint(f);
  return (u + 0x7fffu + ((u >> 16) & 1u)) >> 16;
}
__device__ inline unsigned int pack2bf(float lo, float hi) {
  return f2bf(lo) | (f2bf(hi) << 16);
}
__device__ inline float bflo(unsigned int p) { return __uint_as_float(p << 16); }
__device__ inline float bfhi(unsigned int p) { return __uint_as_float(p & 0xffff0000u); }

// ---------------- init: zero deg8/gstat/binCnt, prefill csr with dummy ----------------

__global__ __launch_bounds__(256) void k_init(int* __restrict__ deg8, float* __restrict__ gstat,
                                              int* __restrict__ csr, int* __restrict__ binCnt) {
  int i = blockIdx.x * 256 + threadIdx.x;
  if (i < NEP) csr[i] = NN;
  if (i < 8 * NN) deg8[i] = 0;
  if (i < 512) gstat[i] = 0.f;   // [gsum0|gsq0|gsum1|gsq1] x128
  if (i < NBKT) binCnt[i] = 0;
}

// ---------------- pass A: degree count + dst-range binning ----------------

__global__ __launch_bounds__(1024) void k_binA(const int* __restrict__ src, const int* __restrict__ dst,
                                               int* __restrict__ deg8, int* __restrict__ binCnt,
                                               int2* __restrict__ bin) {
  __shared__ int lcnt[NBKT], lbase[NBKT];
  int tid = threadIdx.x;
  if (tid < NBKT) lcnt[tid] = 0;
  __syncthreads();
  int e = blockIdx.x * 1024 + tid;
  bool act = e < NE;
  int d = 0, s = 0, b = 0, rank = 0;
  if (act) {
    d = dst[e]; s = src[e];
    b = d >> 13;                       // 0..6
    atomicAdd(&deg8[(e & 7) * NN + d], 1);
    rank = atomicAdd(&lcnt[b], 1);
  }
  __syncthreads();
  if (tid < NBKT && lcnt[tid] > 0) lbase[tid] = atomicAdd(&binCnt[tid], lcnt[tid]);
  __syncthreads();
  if (act) bin[(size_t)b * BCAP + lbase[b] + rank] = make_int2(d, s);
}

// scan PADDED total degrees; also emit true total degree
__global__ __launch_bounds__(1024) void k_scan1(const int* __restrict__ deg8, int* __restrict__ degtot,
                                                int* __restrict__ excl, int* __restrict__ blksum) {
  __shared__ int sm[1024];
  int t = threadIdx.x;
  int i = blockIdx.x * 1024 + t;
  int tot = 0;
  if (i < NN) {
    #pragma unroll
    for (int j = 0; j < 8; j++) tot += deg8[j * NN + i];
    degtot[i] = tot;
  }
  int v = (i < NN) ? ((tot + 7) & ~7) : 0;
  sm[t] = v;
  __syncthreads();
  for (int off = 1; off < 1024; off <<= 1) {
    int x = (t >= off) ? sm[t - off] : 0;
    __syncthreads();
    sm[t] += x;
    __syncthreads();
  }
  if (i < NN) excl[i] = sm[t] - v;
  if (t == 1023) blksum[blockIdx.x] = sm[t];
}

__global__ void k_scan2(const int* __restrict__ blksum, int* __restrict__ blkoff,
                        int* __restrict__ rowstart) {
  int t = threadIdx.x;  // 64 threads, one wave
  int orig = (t < NBLK) ? blksum[t] : 0;
  int v = orig;
  #pragma unroll
  for (int off = 1; off < 64; off <<= 1) {
    int u = __shfl_up(v, off);
    if (t >= off) v += u;
  }
  if (t < NBLK) blkoff[t] = v - orig;
  if (t == NBLK - 1) rowstart[NN] = v;  // padded edge total
}

// finalize rowstart; dis; preload cursor; zero bf16 hs pad rows + h2 pad row
__global__ __launch_bounds__(256) void k_scan3(int* __restrict__ excl, const int* __restrict__ blkoff,
                                               const int* __restrict__ degtot, int* __restrict__ cursor,
                                               float* __restrict__ dis,
                                               unsigned short* __restrict__ hs16, float* __restrict__ h2) {
  int i = blockIdx.x * 256 + threadIdx.x;
  if (i < NN) {
    int rs = excl[i] + blkoff[i >> 10];
    excl[i] = rs;
    cursor[i] = rs;
    dis[i] = rsqrtf((float)degtot[i] + 1.0f);
  }
  if (i < 64) {   // hs16 pad row: 2 slices x 64 bf16 = 2 x 32 uints
    int slice = i >> 5, c = i & 31;
    ((unsigned int*)(hs16 + (size_t)slice * ((size_t)NNP * 64) + (size_t)NN * 64))[c] = 0u;
  }
  if (i < 32) h2[(size_t)NN * 32 + i] = 0.f;
}

// ---------------- pass B: scatter within XCD-pinned bucket ----------------

__global__ __launch_bounds__(256) void k_fillB(const int2* __restrict__ bin, const int* __restrict__ binCnt,
                                               int* __restrict__ cursor, int* __restrict__ csr_src) {
  int b = blockIdx.x & 7;
  if (b >= NBKT) return;
  int q = blockIdx.x >> 3;             // 0..63
  int cnt = binCnt[b];
  const int2* __restrict__ B = bin + (size_t)b * BCAP;
  for (int i = q * 256 + threadIdx.x; i < cnt; i += 64 * 256) {
    int2 ds = B[i];
    int p = atomicAdd(&cursor[ds.x], 1);
    csr_src[p] = ds.y;
  }
}

// ---------------- SGEMM 128->128: 64-row tiles, micro 4x8, bf16 2-slice-major out ----------
// hs16[slice][node][64] bf16 (slice = col>>6, stride NNP rows), pre-scaled by dis[row].

__global__ __launch_bounds__(256) void k_gemm128(const float* __restrict__ X, const float* __restrict__ W,
                                                 const float* __restrict__ dis,
                                                 unsigned short* __restrict__ hs16, int M) {
  __shared__ float As[8][64];
  __shared__ float Bs[8][128];
  const int tid = threadIdx.x;
  const int rg = tid >> 4;   // 0..15: 4-row group
  const int cg = tid & 15;   // 0..15: 8-col group
  const int row0 = blockIdx.x * 64;

  float acc[4][8];
  #pragma unroll
  for (int i = 0; i < 4; i++)
    #pragma unroll
    for (int j = 0; j < 8; j++) acc[i][j] = 0.f;

  const int lr = tid >> 2;        // 0..63
  const int lk = (tid & 3) * 2;   // 0,2,4,6

  for (int kt = 0; kt < 128; kt += 8) {
    float2 av = make_float2(0.f, 0.f);
    int gr = row0 + lr;
    if (gr < M) av = *(const float2*)(X + (size_t)gr * 128 + kt + lk);
    As[lk][lr] = av.x; As[lk + 1][lr] = av.y;
    int k = tid >> 5, c = (tid & 31) * 4;
    *(float4*)&Bs[k][c] = *(const float4*)(W + (size_t)(k + kt) * 128 + c);
    __syncthreads();
    #pragma unroll
    for (int kk = 0; kk < 8; kk++) {
      float a[4], b[8];
      *(float4*)&a[0] = *(const float4*)&As[kk][rg * 4];
      *(float4*)&b[0] = *(const float4*)&Bs[kk][cg * 8];
      *(float4*)&b[4] = *(const float4*)&Bs[kk][cg * 8 + 4];
      #pragma unroll
      for (int i = 0; i < 4; i++)
        #pragma unroll
        for (int j = 0; j < 8; j++) acc[i][j] += a[i] * b[j];
    }
    __syncthreads();
  }

  #pragma unroll
  for (int i = 0; i < 4; i++) {
    int gr = row0 + rg * 4 + i;
    if (gr < M) {
      float d = dis[gr];
      // cols cg*8..cg*8+7 -> slice = cg>>3, within-slice offset (cg&7)*8 bf16
      size_t sbase = (size_t)(cg >> 3) * ((size_t)NNP * 64) + (size_t)gr * 64 + (cg & 7) * 8;
      uint4 u;
      u.x = pack2bf(acc[i][0] * d, acc[i][1] * d);
      u.y = pack2bf(acc[i][2] * d, acc[i][3] * d);
      u.z = pack2bf(acc[i][4] * d, acc[i][5] * d);
      u.w = pack2bf(acc[i][6] * d, acc[i][7] * d);
      *(uint4*)(hs16 + sbase) = u;
    }
  }
}

// ---------------- SGEMM 128->32: 128-row tiles, micro 8x2, row-major fp32 out ----------------

__global__ __launch_bounds__(256) void k_gemm32(const float* __restrict__ X, const float* __restrict__ W,
                                                const float* __restrict__ dis, float* __restrict__ H, int M) {
  __shared__ float As[8][128];
  __shared__ float Bs[8][32];
  const int tid = threadIdx.x;
  const int rg = tid >> 4;
  const int cg = tid & 15;
  const int row0 = blockIdx.x * 128;

  float acc[8][2];
  #pragma unroll
  for (int i = 0; i < 8; i++) { acc[i][0] = 0.f; acc[i][1] = 0.f; }

  const int lr = tid >> 1;
  const int lk = (tid & 1) * 4;

  for (int kt = 0; kt < 128; kt += 8) {
    float4 av = make_float4(0.f, 0.f, 0.f, 0.f);
    int gr = row0 + lr;
    if (gr < M) av = *(const float4*)(X + (size_t)gr * 128 + kt + lk);
    As[lk + 0][lr] = av.x; As[lk + 1][lr] = av.y; As[lk + 2][lr] = av.z; As[lk + 3][lr] = av.w;
    int k = tid >> 5, c = tid & 31;
    Bs[k][c] = W[(size_t)(k + kt) * 32 + c];
    __syncthreads();
    #pragma unroll
    for (int kk = 0; kk < 8; kk++) {
      float a[8];
      *(float4*)&a[0] = *(const float4*)&As[kk][rg * 8];
      *(float4*)&a[4] = *(const float4*)&As[kk][rg * 8 + 4];
      float b0 = Bs[kk][cg * 2], b1 = Bs[kk][cg * 2 + 1];
      #pragma unroll
      for (int i = 0; i < 8; i++) { acc[i][0] += a[i] * b0; acc[i][1] += a[i] * b1; }
    }
    __syncthreads();
  }

  #pragma unroll
  for (int i = 0; i < 8; i++) {
    int gr = row0 + rg * 8 + i;
    if (gr < M) {
      float d = dis[gr];
      *(float2*)(H + (size_t)gr * 32 + cg * 2) = make_float2(acc[i][0] * d, acc[i][1] * d);
    }
  }
}

// ---------------- aggregation, layer 0/1: bf16 gather, 128 B rows ----------------
// 2 slices x 64 features x 2 B = 128 B rows (full-line gathers, half the bytes of fp32).
// Wave = 8 nodes x 8 feature-lanes (uint4 = 8 bf16 each). slice = blockIdx & 1.
// Rows padded to x8 with dummy node NN (zero row). fp32 accumulate.

__global__ __launch_bounds__(256) void k_agg128(const unsigned short* __restrict__ Hs,
                                                const float* __restrict__ dis,
                                                const int* __restrict__ rowstart,
                                                const int* __restrict__ csr_src,
                                                const float* __restrict__ bias,
                                                float* __restrict__ out) {
  int slice = blockIdx.x & 1;
  int lane = threadIdx.x & 63;
  int node_sub = lane >> 3;      // 0..7
  int fl = lane & 7;             // 0..7 (8 bf16 = 16 B each)
  int base = node_sub * 8;
  int w = (blockIdx.x >> 1) * 32 + (threadIdx.x >> 6) * 8 + node_sub;
  if (w >= NN) return;
  const unsigned short* __restrict__ S = Hs + (size_t)slice * ((size_t)NNP * 64) + fl * 8;
  float di = dis[w];
  int e0 = rowstart[w], e1 = rowstart[w + 1];   // padded, group-uniform
  float acc[8];
  #pragma unroll
  for (int j = 0; j < 8; j++) acc[j] = 0.f;

  for (int e = e0; e < e1; e += 8) {
    int myIdx = csr_src[e + fl];               // one instr: 64 indices (8/node)
    int s0 = __shfl(myIdx, base + 0), s1 = __shfl(myIdx, base + 1);
    int s2 = __shfl(myIdx, base + 2), s3 = __shfl(myIdx, base + 3);
    int s4 = __shfl(myIdx, base + 4), s5 = __shfl(myIdx, base + 5);
    int s6 = __shfl(myIdx, base + 6), s7 = __shfl(myIdx, base + 7);
    uint4 g0 = *(const uint4*)(S + (size_t)s0 * 64);
    uint4 g1 = *(const uint4*)(S + (size_t)s1 * 64);
    uint4 g2 = *(const uint4*)(S + (size_t)s2 * 64);
    uint4 g3 = *(const uint4*)(S + (size_t)s3 * 64);
    uint4 g4 = *(const uint4*)(S + (size_t)s4 * 64);
    uint4 g5 = *(const uint4*)(S + (size_t)s5 * 64);
    uint4 g6 = *(const uint4*)(S + (size_t)s6 * 64);
    uint4 g7 = *(const uint4*)(S + (size_t)s7 * 64);
    acc[0] += ((bflo(g0.x) + bflo(g1.x)) + (bflo(g2.x) + bflo(g3.x))) + ((bflo(g4.x) + bflo(g5.x)) + (bflo(g6.x) + bflo(g7.x)));
    acc[1] += ((bfhi(g0.x) + bfhi(g1.x)) + (bfhi(g2.x) + bfhi(g3.x))) + ((bfhi(g4.x) + bfhi(g5.x)) + (bfhi(g6.x) + bfhi(g7.x)));
    acc[2] += ((bflo(g0.y) + bflo(g1.y)) + (bflo(g2.y) + bflo(g3.y))) + ((bflo(g4.y) + bflo(g5.y)) + (bflo(g6.y) + bflo(g7.y)));
    acc[3] += ((bfhi(g0.y) + bfhi(g1.y)) + (bfhi(g2.y) + bfhi(g3.y))) + ((bfhi(g4.y) + bfhi(g5.y)) + (bfhi(g6.y) + bfhi(g7.y)));
    acc[4] += ((bflo(g0.z) + bflo(g1.z)) + (bflo(g2.z) + bflo(g3.z))) + ((bflo(g4.z) + bflo(g5.z)) + (bflo(g6.z) + bflo(g7.z)));
    acc[5] += ((bfhi(g0.z) + bfhi(g1.z)) + (bfhi(g2.z) + bfhi(g3.z))) + ((bfhi(g4.z) + bfhi(g5.z)) + (bfhi(g6.z) + bfhi(g7.z)));
    acc[6] += ((bflo(g0.w) + bflo(g1.w)) + (bflo(g2.w) + bflo(g3.w))) + ((bflo(g4.w) + bflo(g5.w)) + (bflo(g6.w) + bflo(g7.w)));
    acc[7] += ((bfhi(g0.w) + bfhi(g1.w)) + (bfhi(g2.w) + bfhi(g3.w))) + ((bfhi(g4.w) + bfhi(g5.w)) + (bfhi(g6.w) + bfhi(g7.w)));
  }
  uint4 sv = *(const uint4*)(S + (size_t)w * 64);
  float selfv[8] = { bflo(sv.x), bfhi(sv.x), bflo(sv.y), bfhi(sv.y),
                     bflo(sv.z), bfhi(sv.z), bflo(sv.w), bfhi(sv.w) };
  int colOff = slice * 64 + fl * 8;
  float4 b0 = *(const float4*)(bias + colOff);
  float4 b1 = *(const float4*)(bias + colOff + 4);
  float4 r0, r1;
  r0.x = (acc[0] + selfv[0]) * di + b0.x;
  r0.y = (acc[1] + selfv[1]) * di + b0.y;
  r0.z = (acc[2] + selfv[2]) * di + b0.z;
  r0.w = (acc[3] + selfv[3]) * di + b0.w;
  r1.x = (acc[4] + selfv[4]) * di + b1.x;
  r1.y = (acc[5] + selfv[5]) * di + b1.y;
  r1.z = (acc[6] + selfv[6]) * di + b1.z;
  r1.w = (acc[7] + selfv[7]) * di + b1.w;
  *(float4*)(out + (size_t)w * 128 + colOff)     = r0;
  *(float4*)(out + (size_t)w * 128 + colOff + 4) = r1;
}

// ---------------- final layer: aggregation + fused log_softmax (fp32) ----------------

__global__ __launch_bounds__(256) void k_agg32lsm(const float* __restrict__ H2,
                                                  const float* __restrict__ dis,
                                                  const int* __restrict__ rowstart,
                                                  const int* __restrict__ csr_src,
                                                  const float* __restrict__ bias,
                                                  float* __restrict__ out) {
  int wave = (blockIdx.x * 256 + threadIdx.x) >> 6;
  int lane = threadIdx.x & 63;
  int half = lane >> 5;
  int l = lane & 31;
  int hbase = half * 32;
  int w = wave * 2 + half;
  if (w >= NN) return;   // NN even: both halves exit together
  const float* __restrict__ S = H2 + l;
  float di = dis[w];
  int e0 = rowstart[w], e1 = rowstart[w + 1];
  float acc = 0.f;
  for (int e = e0; e < e1; e += 8) {
    int myIdx = csr_src[e + (l & 7)];
    int s0 = __shfl(myIdx, hbase + 0), s1 = __shfl(myIdx, hbase + 1);
    int s2 = __shfl(myIdx, hbase + 2), s3 = __shfl(myIdx, hbase + 3);
    int s4 = __shfl(myIdx, hbase + 4), s5 = __shfl(myIdx, hbase + 5);
    int s6 = __shfl(myIdx, hbase + 6), s7 = __shfl(myIdx, hbase + 7);
    float h0 = S[(size_t)s0 * 32], h1 = S[(size_t)s1 * 32];
    float h2v = S[(size_t)s2 * 32], h3 = S[(size_t)s3 * 32];
    float h4 = S[(size_t)s4 * 32], h5 = S[(size_t)s5 * 32];
    float h6 = S[(size_t)s6 * 32], h7 = S[(size_t)s7 * 32];
    acc += ((h0 + h1) + (h2v + h3)) + ((h4 + h5) + (h6 + h7));
  }
  float v = (acc + S[(size_t)w * 32]) * di + bias[l];
  float m = v;
  #pragma unroll
  for (int off = 16; off >= 1; off >>= 1) m = fmaxf(m, __shfl_xor(m, off));
  float ex = expf(v - m);
  float s = ex;
  #pragma unroll
  for (int off = 16; off >= 1; off >>= 1) s += __shfl_xor(s, off);
  out[(size_t)w * 32 + l] = v - m - logf(s);
}

// ---------------- BatchNorm stats + fused BN/ReLU/residual ----------------

__global__ __launch_bounds__(256) void k_bnstats(const float* __restrict__ O, float* __restrict__ gsum,
                                                 float* __restrict__ gsumsq) {
  int tid = threadIdx.x;
  int f = tid & 127;
  int half = tid >> 7;
  float s = 0.f, sq = 0.f;
  for (int r = blockIdx.x * 2 + half; r < NN; r += gridDim.x * 2) {
    float v = O[(size_t)r * 128 + f];
    s += v; sq += v * v;
  }
  __shared__ float sm[256], sm2[256];
  sm[tid] = s; sm2[tid] = sq;
  __syncthreads();
  if (tid < 128) {
    atomicAdd(&gsum[f], sm[tid] + sm[tid + 128]);
    atomicAdd(&gsumsq[f], sm2[tid] + sm2[tid + 128]);
  }
}

// fused BN (inline mu/istd from raw sums) + ReLU + residual
__global__ __launch_bounds__(256) void k_fuse(const float* __restrict__ O, const float* Xin, float* Xout,
                                              const float* __restrict__ gsum, const float* __restrict__ gsumsq,
                                              const float* __restrict__ g, const float* __restrict__ be) {
  int i = blockIdx.x * 256 + threadIdx.x;
  if (i >= NN * 128 / 4) return;
  int f = (i * 4) & 127;
  float4 ov = ((const float4*)O)[i];
  float4 xv = ((const float4*)Xin)[i];
  float4 r;
  const float inv = 1.f / (float)NN;
  #pragma unroll
  for (int j = 0; j < 4; j++) {
    float m = gsum[f + j] * inv;
    float var = gsumsq[f + j] * inv - m * m;
    float istd = rsqrtf(var + 1e-5f);
    float o = (&ov.x)[j];
    float xx = (&xv.x)[j];
    (&r.x)[j] = fmaxf((o - m) * istd * g[f + j] + be[f + j], 0.f) + xx;
  }
  ((float4*)Xout)[i] = r;
}

// ---------------- launch ----------------

extern "C" void kernel_launch(void* const* d_in, const int* in_sizes, int n_in,
                              void* d_out, int out_size, void* d_ws, size_t ws_size,
                              hipStream_t stream) {
  const float* x   = (const float*)d_in[0];
  const int*   ei  = (const int*)d_in[1];
  const float* W0  = (const float*)d_in[2];
  const float* b0  = (const float*)d_in[3];
  const float* g0  = (const float*)d_in[4];
  const float* be0 = (const float*)d_in[5];
  const float* W1  = (const float*)d_in[6];
  const float* b1  = (const float*)d_in[7];
  const float* g1  = (const float*)d_in[8];
  const float* be1 = (const float*)d_in[9];
  const float* W2  = (const float*)d_in[10];
  const float* b2  = (const float*)d_in[11];
  float* out = (float*)d_out;
  const int* srcI = ei;
  const int* dstI = ei + NE;

  char* p = (char*)d_ws;
  auto take = [&](size_t bytes) { char* r = p; p += (bytes + 255) & ~(size_t)255; return (void*)r; };
  int*   deg8     = (int*)take((size_t)8 * NN * 4);
  int*   cursor   = (int*)take(NN * 4);
  int*   degtot   = (int*)take(NN * 4);
  int*   rowstart = (int*)take((NN + 1) * 4);
  int*   blksum   = (int*)take(64 * 4);
  int*   blkoff   = (int*)take(64 * 4);
  int*   binCnt   = (int*)take(8 * 4);
  float* dis      = (float*)take(NN * 4);
  int*   csr      = (int*)take((size_t)NEP * 4);
  int2*  bin      = (int2*)take((size_t)NBKT * BCAP * 8);
  float* gstat    = (float*)take(512 * 4);   // layer0: [0..255], layer1: [256..511]
  unsigned short* hs16 = (unsigned short*)take((size_t)NNP * 128 * 2);  // bf16, 2-slice-major
  float* o        = (float*)take((size_t)NN * 128 * 4);
  float* xA       = (float*)take((size_t)NN * 128 * 4);
  float* h2       = (float*)take((size_t)NNP * 32 * 4);

  k_init<<<(NEP + 255) / 256, 256, 0, stream>>>(deg8, gstat, csr, binCnt);
  k_binA<<<(NE + 1023) / 1024, 1024, 0, stream>>>(srcI, dstI, deg8, binCnt, bin);
  k_scan1<<<NBLK, 1024, 0, stream>>>(deg8, degtot, rowstart, blksum);
  k_scan2<<<1, 64, 0, stream>>>(blksum, blkoff, rowstart);
  k_scan3<<<(NN + 255) / 256, 256, 0, stream>>>(rowstart, blkoff, degtot, cursor, dis, hs16, h2);
  k_fillB<<<512, 256, 0, stream>>>(bin, binCnt, cursor, csr);

  const int aggGrid = ((NN + 31) / 32) * 2;  // 32 nodes/block x 2 slices

  // ---- layer 0 ----
  k_gemm128<<<(NN + 63) / 64, 256, 0, stream>>>(x, W0, dis, hs16, NN);
  k_agg128<<<aggGrid, 256, 0, stream>>>(hs16, dis, rowstart, csr, b0, o);
  k_bnstats<<<1024, 256, 0, stream>>>(o, gstat, gstat + 128);
  k_fuse<<<(NN * 128 / 4 + 255) / 256, 256, 0, stream>>>(o, x, xA, gstat, gstat + 128, g0, be0);

  // ---- layer 1 ----
  k_gemm128<<<(NN + 63) / 64, 256, 0, stream>>>(xA, W1, dis, hs16, NN);
  k_agg128<<<aggGrid, 256, 0, stream>>>(hs16, dis, rowstart, csr, b1, o);
  k_bnstats<<<1024, 256, 0, stream>>>(o, gstat + 256, gstat + 384);
  k_fuse<<<(NN * 128 / 4 + 255) / 256, 256, 0, stream>>>(o, xA, xA, gstat + 256, gstat + 384, g1, be1);

  // ---- final conv + fused aggregation/log_softmax ----
  k_gemm32<<<(NN + 127) / 128, 256, 0, stream>>>(xA, W2, dis, h2, NN);
  k_agg32lsm<<<(NN + 7) / 8, 256, 0, stream>>>(h2, dis, rowstart, csr, b2, out);
}